// Round 11
// baseline (1397.375 us; speedup 1.0000x reference)
//
#include <hip/hip_runtime.h>
#include <math.h>

#define EPS_ 1e-5f

static constexpr int Bb = 512, Vv = 4, Tt = 16, Dd = 512, NCc = 174;
static constexpr int NROW = Bb * Vv * Tt;      // 32768
static constexpr int EROW = Bb * 12 * Tt;      // 98304
static constexpr int CB = 128;                 // batches per edge chunk
static constexpr int NCHUNK = Bb / CB;         // 4
static constexpr int CROWS_N = CB * Vv * Tt;   // 8192
static constexpr int CROWS_E = CB * 12 * Tt;   // 24576

__constant__ int d_SEND[12] = {0,0,0,1,1,1,2,2,2,3,3,3};
__constant__ int d_RECV[12] = {1,2,3,0,2,3,0,1,3,0,1,2};
__constant__ int d_EOFV[4][3] = {{3,6,9},{0,7,10},{1,4,11},{2,5,8}};

typedef float f32x4 __attribute__((ext_vector_type(4)));
typedef short s16x8 __attribute__((ext_vector_type(8)));

static __device__ __forceinline__ float b2f(unsigned short u) {
    union { unsigned int i; float f; } x; x.i = ((unsigned int)u) << 16; return x.f;
}
static __device__ __forceinline__ unsigned short f2b(float f) {
    union { float f; unsigned int i; } x; x.f = f;
    unsigned int r = (x.i + 0x7fffu + ((x.i >> 16) & 1u)) >> 16;
    return (unsigned short)r;
}
static __device__ __forceinline__ float act_f(float v, int act) {
    if (act == 1) return fmaxf(v, 0.f);
    if (act == 2) return (v > 0.f) ? v : (__expf(v) - 1.f);
    return v;
}

#define GL2LDS(g, l) __builtin_amdgcn_global_load_lds(                     \
    (__attribute__((address_space(1))) void*)(g),                          \
    (__attribute__((address_space(3))) void*)(l), 16, 0, 0)

#define CS_STRIDE 136   // shorts per epilogue LDS row (128 + 8 pad), 16B aligned

// ================= MFMA bf16 GEMM (unchanged from round 10) ================
__global__ __launch_bounds__(256) void gemm_bf16(
    const unsigned short* __restrict__ A0, int Ka0, int K0,
    const unsigned short* __restrict__ A1, int Ka1, int K1,
    const unsigned short* __restrict__ WT, int Kw, int wtoff,
    unsigned short* __restrict__ C, int M, int N,
    const float* __restrict__ bias, int act,
    float* __restrict__ pstats, int accum,
    float* __restrict__ Cpart, int Ksl)
{
    __shared__ __align__(16) unsigned short SMEM[24576];
    int tid = threadIdx.x;
    int lane = tid & 63, wave = tid >> 6;
    int wr = wave >> 1, wc = wave & 1;
    int g = lane >> 4, r16 = lane & 15;

    int nct = N >> 7, nrt = M >> 7;
    int id = blockIdx.x, bx, by;
    if ((nrt & 7) == 0) {
        int grp = id / (nct * 8);
        int rem = id - grp * nct * 8;
        by = grp * 8 + (rem & 7);
        bx = rem >> 3;
    } else { bx = id % nct; by = id / nct; }
    int rowBase = by * 128;
    int colBase = bx * 128;
    int koff = blockIdx.z * Ksl;

    int u2 = lane >> 3;
    int q  = (lane & 7) ^ u2;
    int srow = wave * 32 + u2 * 2 + (q >> 2);
    int scol = (q & 3) * 8;
    const unsigned short* wrow  = WT + (size_t)(colBase + srow) * Kw + wtoff + scol;
    const unsigned short* wrow2 = WT + (size_t)(colBase + srow + 16) * Kw + wtoff + scol;

    f32x4 acc[4][4];
#pragma unroll
    for (int i = 0; i < 4; ++i)
#pragma unroll
        for (int j = 0; j < 4; ++j) acc[i][j] = (f32x4){0.f, 0.f, 0.f, 0.f};

#define STAGE_(kg_, SL_) do {                                                   \
        int kg = (kg_);                                                         \
        const unsigned short* Ap; int lda; int kc;                              \
        if (kg < K0) { Ap = A0; lda = Ka0; kc = kg; }                           \
        else         { Ap = A1; lda = Ka1; kc = kg - K0; }                      \
        const unsigned short* ga = Ap + (size_t)(rowBase + srow) * lda + kc + scol; \
        GL2LDS(ga, (SL_) + wave * 1024);                                        \
        GL2LDS(ga + (size_t)16 * lda, (SL_) + wave * 1024 + 512);               \
        GL2LDS(wrow + kg, (SL_) + 4096 + wave * 1024);                          \
        GL2LDS(wrow2 + kg, (SL_) + 4096 + wave * 1024 + 512);                   \
    } while (0)

    int nt = Ksl >> 5;
    STAGE_(koff, SMEM);
    if (nt > 1) STAGE_(koff + 32, SMEM + 8192);
    int cur = 0;
    int rh  = r16 >> 1;
    int sw8 = (((((r16 & 1) << 2) | g) ^ rh)) << 3;
    for (int t = 0; t < nt; ++t) {
        if (t + 1 < nt) asm volatile("s_waitcnt vmcnt(4)" ::: "memory");
        else            asm volatile("s_waitcnt vmcnt(0)" ::: "memory");
        __builtin_amdgcn_s_barrier();
        __builtin_amdgcn_sched_barrier(0);
        if (t + 2 < nt) {
            int nx = cur + 2; if (nx >= 3) nx -= 3;
            STAGE_(koff + (t + 2) * 32, SMEM + nx * 8192);
        }
        unsigned short* SA = SMEM + cur * 8192;
        unsigned short* SB = SA + 4096;
        s16x8 xf[4], wf[4];
#pragma unroll
        for (int j = 0; j < 4; ++j)
            xf[j] = *(const s16x8*)(SA + (wr * 32 + j * 8 + rh) * 64 + sw8);
#pragma unroll
        for (int i = 0; i < 4; ++i)
            wf[i] = *(const s16x8*)(SB + (wc * 32 + i * 8 + rh) * 64 + sw8);
#pragma unroll
        for (int i = 0; i < 4; ++i)
#pragma unroll
            for (int j = 0; j < 4; ++j)
                acc[i][j] = __builtin_amdgcn_mfma_f32_16x16x32_bf16(
                    wf[i], xf[j], acc[i][j], 0, 0, 0);
        cur = (cur == 2) ? 0 : cur + 1;
    }
#undef STAGE_
    __syncthreads();

    if (Cpart) {
#pragma unroll
        for (int j = 0; j < 4; ++j) {
            int row = rowBase + wr * 64 + j * 16 + r16;
#pragma unroll
            for (int i = 0; i < 4; ++i) {
                int col0 = colBase + wc * 64 + i * 16 + g * 4;
                float4 v = make_float4(acc[i][j][0], acc[i][j][1],
                                       acc[i][j][2], acc[i][j][3]);
                *(float4*)&Cpart[((size_t)blockIdx.z * M + row) * N + col0] = v;
            }
        }
        return;
    }

#pragma unroll
    for (int i = 0; i < 4; ++i) {
        int lc0 = wc * 64 + i * 16 + g * 4;
        float4 b4 = bias ? *(const float4*)(bias + colBase + lc0)
                         : make_float4(0.f, 0.f, 0.f, 0.f);
        float s[4] = {0.f, 0.f, 0.f, 0.f}, q2[4] = {0.f, 0.f, 0.f, 0.f};
#pragma unroll
        for (int j = 0; j < 4; ++j) {
            int lr = wr * 64 + j * 16 + r16;
            float v0 = act_f(acc[i][j][0] + b4.x, act);
            float v1 = act_f(acc[i][j][1] + b4.y, act);
            float v2 = act_f(acc[i][j][2] + b4.z, act);
            float v3 = act_f(acc[i][j][3] + b4.w, act);
            *(ushort4*)&SMEM[lr * CS_STRIDE + lc0] =
                make_ushort4(f2b(v0), f2b(v1), f2b(v2), f2b(v3));
            s[0] += v0; s[1] += v1; s[2] += v2; s[3] += v3;
            q2[0] += v0 * v0; q2[1] += v1 * v1; q2[2] += v2 * v2; q2[3] += v3 * v3;
        }
        if (pstats) {
#pragma unroll
            for (int p = 0; p < 4; ++p) {
#pragma unroll
                for (int d = 1; d < 16; d <<= 1) {
                    s[p] += __shfl_xor(s[p], d);
                    q2[p] += __shfl_xor(q2[p], d);
                }
            }
            if (r16 == 0) {
                float* pr = pstats + ((size_t)(by * 2 + wr)) * 1024 + colBase + lc0;
                float4 s4 = make_float4(s[0], s[1], s[2], s[3]);
                float4 q4 = make_float4(q2[0], q2[1], q2[2], q2[3]);
                if (accum) {
                    float4 o = *(float4*)pr;
                    s4.x += o.x; s4.y += o.y; s4.z += o.z; s4.w += o.w;
                    float4 o2 = *(float4*)(pr + 512);
                    q4.x += o2.x; q4.y += o2.y; q4.z += o2.z; q4.w += o2.w;
                }
                *(float4*)pr = s4;
                *(float4*)(pr + 512) = q4;
            }
        }
    }
    __syncthreads();
    {
        int qd = tid & 3;
        int rr = tid >> 2;
#pragma unroll
        for (int pass = 0; pass < 2; ++pass) {
            int lr = pass * 64 + rr;
            size_t grow = (size_t)(rowBase + lr) * N + colBase;
#pragma unroll
            for (int u = 0; u < 4; ++u) {
                int cofs = u * 32 + qd * 8;
                uint4 v = *(const uint4*)(SMEM + lr * CS_STRIDE + cofs);
                *(uint4*)&C[grow + cofs] = v;
            }
        }
    }
}

// ---- FUSED stats-finalize + BN apply ---------------------------------------
// grid (C/64 col-groups, nslabs row-slabs). Each block first reduces its 64
// columns of P (nrows rows, redundant across slabs but L2-hot), then applies
// scale/shift+act in place to its (slab x col-group) region of X.
__global__ __launch_bounds__(256) void bn_fused_k(
    unsigned short* __restrict__ X, int C, int rps,
    const float* __restrict__ P, int nrows,
    const float* __restrict__ gm, const float* __restrict__ bt,
    float inv_cnt, float premul, int act)
{
    __shared__ float red[512];
    __shared__ float sc_s[64], sh_s[64];
    int cg = blockIdx.x;
    int lane = threadIdx.x & 63;
    int seg  = threadIdx.x >> 6;
    int c = cg * 64 + lane;
    float s = 0.f, q = 0.f;
    for (int r = seg; r < nrows; r += 4) {
        s += P[(size_t)r * 1024 + c];
        q += P[(size_t)r * 1024 + 512 + c];
    }
    red[threadIdx.x] = s; red[256 + threadIdx.x] = q;
    __syncthreads();
    if (seg == 0) {
        float S = red[lane] + red[64 + lane] + red[128 + lane] + red[192 + lane];
        float Q = red[256 + lane] + red[320 + lane] + red[384 + lane] + red[448 + lane];
        float mean = S * inv_cnt;
        float var = fmaxf(Q * inv_cnt - mean * mean, 0.f);
        float sc = gm[c] * rsqrtf(var + EPS_);
        sc_s[lane] = sc * premul;
        sh_s[lane] = bt[c] - mean * sc;
    }
    __syncthreads();
    int r0 = blockIdx.y * rps;
    int c4 = threadIdx.x & 15;
    int ro = threadIdx.x >> 4;
    for (int r = r0 + ro; r < r0 + rps; r += 16) {
        ushort4* px = (ushort4*)&X[(size_t)r * C + cg * 64] + c4;
        ushort4 x = *px;
        unsigned short o[4] = {x.x, x.y, x.z, x.w};
#pragma unroll
        for (int e = 0; e < 4; ++e) {
            float v = b2f(o[e]) * sc_s[c4 * 4 + e] + sh_s[c4 * 4 + e];
            o[e] = f2b(act_f(v, act));
        }
        *px = make_ushort4(o[0], o[1], o[2], o[3]);
    }
}

// ---- FUSED stats-finalize + BN fold into consuming gemm --------------------
// grid 136: blocks [0,128): (kg=blk&7, ng=blk>>3) reduce 64 k-cols then scale
// WT rows n in [ng*32,+32), k in [kg*64,+64). blocks [128,136): bias for 64 n:
// compute sh[k] all k in LDS, then bias_out[n] = bias_in[n] + sum sh[k]*W[k][n].
__global__ __launch_bounds__(256) void fold_bn2_k(
    const float* __restrict__ P, int nrows,
    const float* __restrict__ gm, const float* __restrict__ bt,
    float inv_cnt, float premul,
    unsigned short* __restrict__ WT, int Kw, int kof,
    const float* __restrict__ Wsrc, const float* __restrict__ bias_in,
    float* __restrict__ bias_out)
{
    int blk = blockIdx.x;
    int lane = threadIdx.x & 63;
    int seg  = threadIdx.x >> 6;
    if (blk < 128) {
        __shared__ float red[512];
        __shared__ float sc_s[64];
        int kg = blk & 7, ng = blk >> 3;
        int k = kg * 64 + lane;
        float s = 0.f, q = 0.f;
        for (int r = seg; r < nrows; r += 4) {
            s += P[(size_t)r * 1024 + k];
            q += P[(size_t)r * 1024 + 512 + k];
        }
        red[threadIdx.x] = s; red[256 + threadIdx.x] = q;
        __syncthreads();
        if (seg == 0) {
            float S = red[lane] + red[64 + lane] + red[128 + lane] + red[192 + lane];
            float Q = red[256 + lane] + red[320 + lane] + red[384 + lane] + red[448 + lane];
            float mean = S * inv_cnt;
            float var = fmaxf(Q * inv_cnt - mean * mean, 0.f);
            sc_s[lane] = gm[k] * rsqrtf(var + EPS_) * premul;
        }
        __syncthreads();
        for (int n = ng * 32 + seg; n < ng * 32 + 32; n += 4) {
            unsigned short* p = &WT[(size_t)n * Kw + kof + kg * 64 + lane];
            *p = f2b(b2f(*p) * sc_s[lane]);
        }
    } else {
        __shared__ float sh_l[512];
        __shared__ float red[256];
        for (int k = threadIdx.x; k < 512; k += 256) {
            float s = 0.f, q = 0.f;
#pragma unroll 4
            for (int r = 0; r < nrows; ++r) {
                s += P[(size_t)r * 1024 + k];
                q += P[(size_t)r * 1024 + 512 + k];
            }
            float mean = s * inv_cnt;
            float var = fmaxf(q * inv_cnt - mean * mean, 0.f);
            float sc = gm[k] * rsqrtf(var + EPS_);
            sh_l[k] = bt[k] - mean * sc;
        }
        __syncthreads();
        int n = (blk - 128) * 64 + lane;
        float acc = 0.f;
        int k0 = seg * 128;
#pragma unroll 4
        for (int k = k0; k < k0 + 128; ++k)
            acc += sh_l[k] * Wsrc[(size_t)k * 512 + n];
        red[threadIdx.x] = acc;
        __syncthreads();
        if (seg == 0)
            bias_out[n] = (bias_in ? bias_in[n] : 0.f)
                        + red[lane] + red[64 + lane]
                        + red[128 + lane] + red[192 + lane];
    }
}

// ---- split-K combine, parallel + vectorized; stats -> partials -------------
__global__ __launch_bounds__(256) void combine_k(
    const float4* __restrict__ P, int S, int M,
    unsigned short* __restrict__ C, float* __restrict__ pstats, int act)
{
    int col4 = threadIdx.x & 127;
    int rh = threadIdx.x >> 7;
    int rb = blockIdx.y * 8;
    float4 s4 = make_float4(0.f, 0.f, 0.f, 0.f);
    float4 q4 = make_float4(0.f, 0.f, 0.f, 0.f);
#pragma unroll
    for (int i = 0; i < 4; ++i) {
        int row = rb + rh + 2 * i;
        float4 v = make_float4(0.f, 0.f, 0.f, 0.f);
#pragma unroll
        for (int z = 0; z < 8; ++z) {
            float4 p = P[((size_t)z * M + row) * 128 + col4];
            v.x += p.x; v.y += p.y; v.z += p.z; v.w += p.w;
        }
        v.x = act_f(v.x, act); v.y = act_f(v.y, act);
        v.z = act_f(v.z, act); v.w = act_f(v.w, act);
        ((ushort4*)C)[(size_t)row * 128 + col4] =
            make_ushort4(f2b(v.x), f2b(v.y), f2b(v.z), f2b(v.w));
        s4.x += v.x; s4.y += v.y; s4.z += v.z; s4.w += v.w;
        q4.x += v.x * v.x; q4.y += v.y * v.y; q4.z += v.z * v.z; q4.w += v.w * v.w;
    }
    __shared__ float4 sb[256], qb[256];
    sb[threadIdx.x] = s4; qb[threadIdx.x] = q4;
    __syncthreads();
    if (threadIdx.x < 128) {
        float4 a = sb[threadIdx.x], b = sb[threadIdx.x + 128];
        float4 c = qb[threadIdx.x], d = qb[threadIdx.x + 128];
        int col = threadIdx.x * 4;
        float* pr = pstats + (size_t)blockIdx.y * 1024 + col;
        *(float4*)pr = make_float4(a.x + b.x, a.y + b.y, a.z + b.z, a.w + b.w);
        *(float4*)(pr + 512) = make_float4(c.x + d.x, c.y + d.y, c.z + d.z, c.w + d.w);
    }
}

// ---- batched weight convert+transpose, LDS-tiled ---------------------------
#define NTD 13
struct TBatch {
    const float* src[NTD];
    unsigned short* dst[NTD];
    int K[NTD];
    int tbase[NTD + 1];
};
__global__ __launch_bounds__(256) void transpose_batch_k(TBatch tb)
{
    int id = blockIdx.x;
    int d = 0;
#pragma unroll
    for (int j = 0; j < NTD; ++j) if (id >= tb.tbase[j + 1]) d = j + 1;
    int rel = id - tb.tbase[d];
    int kt = rel >> 3, ntl = rel & 7;
    int k0 = kt * 64, n0 = ntl * 64;
    const float* S = tb.src[d];
    unsigned short* D = tb.dst[d];
    int K = tb.K[d];
    __shared__ unsigned short L[64][68];
    int c = threadIdx.x & 63;
    int r = threadIdx.x >> 6;
#pragma unroll
    for (int p = 0; p < 16; ++p) {
        int kk = r + p * 4;
        L[kk][c] = f2b(S[(size_t)(k0 + kk) * 512 + n0 + c]);
    }
    __syncthreads();
#pragma unroll
    for (int p = 0; p < 16; ++p) {
        int nn = r + p * 4;
        D[(size_t)(n0 + nn) * K + k0 + c] = L[c][nn];
    }
}

// fused P/Q transpose for m1_w1 [1024,512], LDS-tiled (two 512x512 halves)
__global__ __launch_bounds__(256) void transpose_pq_k(
    const float* __restrict__ W, unsigned short* __restrict__ WT)
{
    int id = blockIdx.x;
    int kt = id >> 4, ntl = id & 15;
    int k0 = kt * 64, n0 = ntl * 64;
    __shared__ unsigned short L[64][68];
    int c = threadIdx.x & 63;
    int r = threadIdx.x >> 6;
    int nb = n0 + c;
    const float* S = (n0 < 512) ? (W + nb) : (W + (size_t)512 * 512 + (nb - 512));
#pragma unroll
    for (int p = 0; p < 16; ++p) {
        int kk = r + p * 4;
        L[kk][c] = f2b(S[(size_t)(k0 + kk) * 512]);
    }
    __syncthreads();
#pragma unroll
    for (int p = 0; p < 16; ++p) {
        int nn = r + p * 4;
        WT[(size_t)(n0 + nn) * 512 + k0 + c] = L[c][nn];
    }
}

// ---- column stats over Y1 [NROW, 256] bf16 -> PSTATS rows 0..255 -----------
__global__ __launch_bounds__(256) void colstats_k(
    const unsigned short* __restrict__ X, float* __restrict__ P)
{
    __shared__ float sb[256][4], qb[256][4];
    int c4 = threadIdx.x & 63;
    int seg = threadIdx.x >> 6;
    int r0 = blockIdx.x * 128;
    float s[4] = {0.f, 0.f, 0.f, 0.f}, q[4] = {0.f, 0.f, 0.f, 0.f};
    for (int r = r0 + seg; r < r0 + 128; r += 4) {
        ushort4 x = ((const ushort4*)X)[(size_t)r * 64 + c4];
        float v0 = b2f(x.x), v1 = b2f(x.y), v2 = b2f(x.z), v3 = b2f(x.w);
        s[0] += v0; s[1] += v1; s[2] += v2; s[3] += v3;
        q[0] += v0 * v0; q[1] += v1 * v1; q[2] += v2 * v2; q[3] += v3 * v3;
    }
#pragma unroll
    for (int e = 0; e < 4; ++e) { sb[threadIdx.x][e] = s[e]; qb[threadIdx.x][e] = q[e]; }
    __syncthreads();
    if (threadIdx.x < 64) {
        int c = threadIdx.x;
        float4 S, Q;
        S.x = sb[c][0] + sb[c + 64][0] + sb[c + 128][0] + sb[c + 192][0];
        S.y = sb[c][1] + sb[c + 64][1] + sb[c + 128][1] + sb[c + 192][1];
        S.z = sb[c][2] + sb[c + 64][2] + sb[c + 128][2] + sb[c + 192][2];
        S.w = sb[c][3] + sb[c + 64][3] + sb[c + 128][3] + sb[c + 192][3];
        Q.x = qb[c][0] + qb[c + 64][0] + qb[c + 128][0] + qb[c + 192][0];
        Q.y = qb[c][1] + qb[c + 64][1] + qb[c + 128][1] + qb[c + 192][1];
        Q.z = qb[c][2] + qb[c + 64][2] + qb[c + 128][2] + qb[c + 192][2];
        Q.w = qb[c][3] + qb[c + 64][3] + qb[c + 128][3] + qb[c + 192][3];
        *(float4*)&P[(size_t)blockIdx.x * 1024 + c * 4] = S;
        *(float4*)&P[(size_t)blockIdx.x * 1024 + 512 + c * 4] = Q;
    }
}

// ---------------- misc ------------------------------------------------------
// merged input builders: blocks [0,512) build X0, [512,8704) build CE
__global__ __launch_bounds__(256) void build_inputs_k(
    const float* __restrict__ box, float* __restrict__ X0,
    const int* __restrict__ cats, const float* __restrict__ emb,
    unsigned short* __restrict__ CE)
{
    if (blockIdx.x < 512) {
        int i = blockIdx.x * 256 + threadIdx.x;      // NROW*4 = 131072
        int c = i & 3; int r = i >> 2;
        int t = r & 15; int bv = r >> 4; int v = bv & 3; int b = bv >> 2;
        X0[i] = box[(((size_t)b * Tt + t) * Vv + v) * 4 + c];
    } else {
        int i = (blockIdx.x - 512) * 256 + threadIdx.x;   // NROW*64
        int c4 = i & 63; int r = i >> 6;
        int t = r & 15; int bv = r >> 4; int v = bv & 3; int b = bv >> 2;
        int cat = cats[((size_t)b * Tt + t) * Vv + v];
        unsigned short o[4];
#pragma unroll
        for (int e = 0; e < 4; ++e)
            o[e] = (cat == 0) ? 0 : f2b(emb[cat * 256 + c4 * 4 + e]);
        ((ushort4*)CE)[(size_t)r * 64 + c4] = make_ushort4(o[0], o[1], o[2], o[3]);
    }
}

__global__ __launch_bounds__(256) void smallk_gemm_k(
    const float* __restrict__ X0, const float* __restrict__ W4,
    unsigned short* __restrict__ Y1)
{
    int i = blockIdx.x * 256 + threadIdx.x;
    if (i >= NROW * 64) return;
    int n4 = i & 63; int m = i >> 6;
    float4 x = *(const float4*)(X0 + m * 4);
    unsigned short o[4];
#pragma unroll
    for (int e = 0; e < 4; ++e) {
        int n = n4 * 4 + e;
        float v = x.x * W4[n] + x.y * W4[256 + n] + x.z * W4[512 + n] + x.w * W4[768 + n];
        o[e] = f2b(v);
    }
    ((ushort4*)Y1)[(size_t)m * 64 + n4] = make_ushort4(o[0], o[1], o[2], o[3]);
}

__global__ __launch_bounds__(256) void edge_gather_k(
    const unsigned short* __restrict__ PQ,
    const float* __restrict__ b1, unsigned short* __restrict__ E)
{
    int i = blockIdx.x * 256 + threadIdx.x;
    if (i >= CROWS_E * 128) return;
    int c4 = i & 127; int m = i >> 7;
    int t = m & 15; int be = m >> 4; int e = be % 12; int brel = be / 12;
    int s = d_SEND[e], r = d_RECV[e];
    ushort4 p = ((const ushort4*)PQ)[(((size_t)brel * 4 + s) * 16 + t) * 256 + c4];
    ushort4 q = ((const ushort4*)PQ)[(((size_t)brel * 4 + r) * 16 + t) * 256 + 128 + c4];
    unsigned short pa[4] = {p.x, p.y, p.z, p.w}, qa[4] = {q.x, q.y, q.z, q.w}, o[4];
#pragma unroll
    for (int e2 = 0; e2 < 4; ++e2) {
        float v = b2f(pa[e2]) + b2f(qa[e2]) + b1[c4 * 4 + e2];
        o[e2] = f2b(act_f(v, 2));
    }
    ((ushort4*)E)[i] = make_ushort4(o[0], o[1], o[2], o[3]);
}

__global__ __launch_bounds__(256) void edge_agg_k(
    const unsigned short* __restrict__ E2c, unsigned short* __restrict__ nraw, int b0)
{
    int i = blockIdx.x * 256 + threadIdx.x;
    if (i >= CB * Vv * Tt * 128) return;
    int c4 = i & 127; int r = i >> 7;
    int t = r & 15; int r2 = r >> 4; int v = r2 & 3; int brel = r2 >> 2;
    float s[4] = {0.f, 0.f, 0.f, 0.f};
#pragma unroll
    for (int j = 0; j < 3; ++j) {
        int e = d_EOFV[v][j];
        ushort4 x = ((const ushort4*)E2c)[(((size_t)brel * 12 + e) * 16 + t) * 128 + c4];
        s[0] += b2f(x.x); s[1] += b2f(x.y); s[2] += b2f(x.z); s[3] += b2f(x.w);
    }
    ((ushort4*)nraw)[((((size_t)(b0 + brel)) * 4 + v) * 16 + t) * 128 + c4] =
        make_ushort4(f2b(s[0]), f2b(s[1]), f2b(s[2]), f2b(s[3]));
}

__global__ __launch_bounds__(256) void feat_mean_k(
    const unsigned short* __restrict__ q, unsigned short* __restrict__ feat)
{
    int i = blockIdx.x * 256 + threadIdx.x;
    if (i >= Bb * 128) return;
    int c4 = i & 127; int b = i >> 7;
    float s[4] = {0.f, 0.f, 0.f, 0.f};
#pragma unroll
    for (int v = 0; v < 4; ++v) {
        ushort4 x = ((const ushort4*)q)[(((size_t)b * 4 + v)) * 128 + c4];
        s[0] += b2f(x.x); s[1] += b2f(x.y); s[2] += b2f(x.z); s[3] += b2f(x.w);
    }
    ((ushort4*)feat)[(size_t)b * 128 + c4] = make_ushort4(
        f2b(0.25f * s[0]), f2b(0.25f * s[1]), f2b(0.25f * s[2]), f2b(0.25f * s[3]));
}

__global__ __launch_bounds__(256) void final_gemm_k(
    const unsigned short* __restrict__ H2, const float* __restrict__ W,
    const float* __restrict__ b, float* __restrict__ out)
{
    __shared__ float Ls[4 * 512];
    int m0 = blockIdx.x * 4;
    for (int i = threadIdx.x; i < 512; i += 256) {
        ushort4 x = ((const ushort4*)H2)[(size_t)m0 * 128 + i];
        *(float4*)&Ls[i * 4] = make_float4(b2f(x.x), b2f(x.y), b2f(x.z), b2f(x.w));
    }
    __syncthreads();
    int n = threadIdx.x;
    if (n >= NCc) return;
    float a0 = b[n], a1 = a0, a2 = a0, a3 = a0;
#pragma unroll 8
    for (int k = 0; k < 512; ++k) {
        float w = W[(size_t)k * NCc + n];
        a0 += Ls[k] * w;
        a1 += Ls[512 + k] * w;
        a2 += Ls[1024 + k] * w;
        a3 += Ls[1536 + k] * w;
    }
    out[(size_t)m0 * NCc + n] = a0;
    out[(size_t)(m0 + 1) * NCc + n] = a1;
    out[(size_t)(m0 + 2) * NCc + n] = a2;
    out[(size_t)(m0 + 3) * NCc + n] = a3;
}

__global__ __launch_bounds__(256) void copy_labels_k(
    const int* __restrict__ lab, float* __restrict__ out)
{
    int i = blockIdx.x * 256 + threadIdx.x;
    if (i < Bb) out[i] = (float)lab[i];
}

// ---------------- host-side helpers -----------------------------------------
static inline void gemm(hipStream_t s,
                        const unsigned short* A0, int Ka0, int K0,
                        const unsigned short* A1, int Ka1, int K1,
                        const unsigned short* WT, int Kw, int wtoff,
                        unsigned short* C, int M, int N,
                        const float* bias, int act, float* pstats, int accum)
{
    dim3 g((N / 128) * (M / 128), 1, 1);
    hipLaunchKernelGGL(gemm_bf16, g, dim3(256), 0, s,
                       A0, Ka0, K0, A1, Ka1, K1, WT, Kw, wtoff, C, M, N,
                       bias, act, pstats, accum, (float*)nullptr, K0 + K1);
}

static inline void bn_fused(hipStream_t s, unsigned short* X, int R, int C,
                            const float* P, int nrows, const float* gm,
                            const float* bt, float cnt, float premul, int act)
{
    int nslabs = (R >= 8192) ? 64 : 16;
    hipLaunchKernelGGL(bn_fused_k, dim3(C / 64, nslabs), dim3(256), 0, s,
                       X, C, R / nslabs, P, nrows, gm, bt, 1.f / cnt, premul, act);
}

static inline void fold_bn2(hipStream_t s, const float* P, int nrows,
                            const float* gm, const float* bt, float cnt,
                            float premul, unsigned short* WT, int Kw, int kof,
                            const float* Wsrc, const float* bias_in, float* bias_out)
{
    hipLaunchKernelGGL(fold_bn2_k, dim3(136), dim3(256), 0, s,
                       P, nrows, gm, bt, 1.f / cnt, premul, WT, Kw, kof,
                       Wsrc, bias_in, bias_out);
}

extern "C" void kernel_launch(void* const* d_in, const int* in_sizes, int n_in,
                              void* d_out, int out_size, void* d_ws, size_t ws_size,
                              hipStream_t stream)
{
    const int*   box_cat = (const int*)  d_in[1];
    const float* box_in  = (const float*)d_in[2];
    const int*   vlabel  = (const int*)  d_in[4];
    const float* emb     = (const float*)d_in[5];
    const float* c2f_w1  = (const float*)d_in[6];
    const float* c2f_g1  = (const float*)d_in[7];
    const float* c2f_b1  = (const float*)d_in[8];
    const float* c2f_w2  = (const float*)d_in[9];
    const float* c2f_g2  = (const float*)d_in[10];
    const float* c2f_b2  = (const float*)d_in[11];
    const float* fus_w   = (const float*)d_in[12];
    const float* fus_g   = (const float*)d_in[13];
    const float* fus_b   = (const float*)d_in[14];
    const float* m1_w1   = (const float*)d_in[15];
    const float* m1_b1   = (const float*)d_in[16];
    const float* m1_w2   = (const float*)d_in[17];
    const float* m1_b2   = (const float*)d_in[18];
    const float* m1_g    = (const float*)d_in[19];
    const float* m1_bb   = (const float*)d_in[20];
    const float* m2_w1   = (const float*)d_in[21];
    const float* m2_b1   = (const float*)d_in[22];
    const float* m2_w2   = (const float*)d_in[23];
    const float* m2_b2   = (const float*)d_in[24];
    const float* m2_g    = (const float*)d_in[25];
    const float* m2_bb   = (const float*)d_in[26];
    const float* t1_w1   = (const float*)d_in[27];
    const float* t1_b1   = (const float*)d_in[28];
    const float* t1_w2   = (const float*)d_in[29];
    const float* t1_b2   = (const float*)d_in[30];
    const float* t1_g    = (const float*)d_in[31];
    const float* t1_bb   = (const float*)d_in[32];
    const float* ps_w1   = (const float*)d_in[33];
    const float* ps_g1   = (const float*)d_in[34];
    const float* ps_b1   = (const float*)d_in[35];
    const float* ps_w2   = (const float*)d_in[36];
    const float* ps_g2   = (const float*)d_in[37];
    const float* ps_b2   = (const float*)d_in[38];
    const float* tb_w1   = (const float*)d_in[39];
    const float* tb_g1   = (const float*)d_in[40];
    const float* tb_b1   = (const float*)d_in[41];
    const float* tb_w2   = (const float*)d_in[42];
    const float* tb_g2   = (const float*)d_in[43];
    const float* tb_b2   = (const float*)d_in[44];
    const float* cl_w1   = (const float*)d_in[45];
    const float* cl_b1   = (const float*)d_in[46];
    const float* cl_w2   = (const float*)d_in[47];
    const float* cl_b2   = (const float*)d_in[48];
    const float* cl_w3   = (const float*)d_in[49];
    const float* cl_b3   = (const float*)d_in[50];

    float* out = (float*)d_out;

    // ---------------- workspace layout (bytes) ------------------------------
    char* base = (char*)d_ws;
    const size_t SZ_ACT = (size_t)NROW * 512 * 2;       // 32 MB
    unsigned short* A0v = (unsigned short*)(base);
    unsigned short* A1v = (unsigned short*)(base + SZ_ACT);
    char* Sreg = base + 2 * SZ_ACT;                     // scratch region
    unsigned short* A2v = (unsigned short*)Sreg;
    unsigned short* CE  = (unsigned short*)Sreg;
    unsigned short* Y1  = (unsigned short*)(Sreg + (size_t)NROW * 256 * 2);
    unsigned short* PQc = (unsigned short*)Sreg;
    unsigned short* EC1 = (unsigned short*)(Sreg + (size_t)CROWS_N * 1024 * 2);
    unsigned short* EC2 = (unsigned short*)(Sreg + (size_t)CROWS_N * 1024 * 2
                                                 + (size_t)CROWS_E * 512 * 2);
    float* Ppart = (float*)Sreg;
    char* wtb = Sreg + (size_t)CROWS_N * 1024 * 2 + 2 * (size_t)CROWS_E * 512 * 2;
    unsigned short* wtp = (unsigned short*)wtb;
    size_t wo = 0;
    auto alloc_wt = [&](int K) { unsigned short* p = wtp + wo; wo += (size_t)K * 512; return p; };
    unsigned short* WTc2f2 = alloc_wt(256);
    unsigned short* WTfus  = alloc_wt(768);
    unsigned short* WTpq   = alloc_wt(1024);
    unsigned short* WTm1b  = alloc_wt(512);
    unsigned short* WTm2a  = alloc_wt(512);
    unsigned short* WTm2b  = alloc_wt(512);
    unsigned short* WTt1a  = alloc_wt(1024);
    unsigned short* WTt1b  = alloc_wt(512);
    unsigned short* WTps1  = alloc_wt(512);
    unsigned short* WTps2  = alloc_wt(512);
    unsigned short* WTtb1  = alloc_wt(8192);
    unsigned short* WTtb2  = alloc_wt(512);
    unsigned short* WTcl1  = alloc_wt(512);
    unsigned short* WTcl2  = alloc_wt(512);
    float* X0f    = (float*)(wtp + wo);
    float* STATS  = X0f + (size_t)NROW * 4;   // (legacy region, unused)
    float* PSTATS = STATS + 10 * 1024;        // 512 rows x 1024 f32 = 2 MB
    float* BIASF  = PSTATS + 512 * 1024;      // 3 x 512 f32 folded biases

    // 0. weight prep (no zeroing needed: all PSTATS rows are initialized by
    //    '=' writes; m1b chunk 0 uses accum=0 to initialize its rows)
    {
        TBatch tb;
        const float* srcs[NTD] = {c2f_w2, fus_w, m1_w2, m2_w1, m2_w2, t1_w1, t1_w2,
                                  ps_w1, ps_w2, tb_w1, tb_w2, cl_w1, cl_w2};
        unsigned short* dsts[NTD] = {WTc2f2, WTfus, WTm1b, WTm2a, WTm2b, WTt1a, WTt1b,
                                     WTps1, WTps2, WTtb1, WTtb2, WTcl1, WTcl2};
        int Ks[NTD] = {256, 768, 512, 512, 512, 1024, 512, 512, 512, 8192, 512, 512, 512};
        int acc = 0;
        for (int i = 0; i < NTD; ++i) {
            tb.src[i] = srcs[i]; tb.dst[i] = dsts[i]; tb.K[i] = Ks[i];
            tb.tbase[i] = acc; acc += (Ks[i] / 64) * 8;
        }
        tb.tbase[NTD] = acc;
        hipLaunchKernelGGL(transpose_batch_k, dim3((unsigned)acc), dim3(256), 0,
                           stream, tb);
    }
    hipLaunchKernelGGL(transpose_pq_k, dim3(128), dim3(256), 0, stream, m1_w1, WTpq);

    // 1. inputs (merged builder)
    hipLaunchKernelGGL(build_inputs_k, dim3(512 + NROW * 64 / 256), dim3(256), 0,
                       stream, box_in, X0f, box_cat, emb, CE);

    // 2. c2f layer 1 (K=4 fp32) -> Y1 [NROW,256]; stats -> PSTATS; fused BN
    hipLaunchKernelGGL(smallk_gemm_k, dim3((NROW * 64 + 255) / 256), dim3(256), 0,
                       stream, X0f, c2f_w1, Y1);
    hipLaunchKernelGGL(colstats_k, dim3(NROW / 128), dim3(256), 0, stream, Y1, PSTATS);
    bn_fused(stream, Y1, NROW, 256, PSTATS, NROW / 128, c2f_g1, c2f_b1,
             (float)NROW, 1.f, 1);

    // 3. c2f layer 2 -> A1 (stats fused); fused BN+ReLU
    gemm(stream, Y1, 256, 256, nullptr, 0, 0, WTc2f2, 256, 0, A1v, NROW, 512,
         nullptr, 0, PSTATS, 0);
    bn_fused(stream, A1v, NROW, 512, PSTATS, 512, c2f_g2, c2f_b2,
             (float)NROW, 1.f, 1);

    // 4. fusion dual-K -> A0 (BF); fused BN+ReLU
    gemm(stream, A1v, 512, 512, CE, 256, 256, WTfus, 768, 0, A0v, NROW, 512,
         nullptr, 0, PSTATS, 0);
    bn_fused(stream, A0v, NROW, 512, PSTATS, 512, fus_g, fus_b,
             (float)NROW, 1.f, 1);                                    // BF in A0

    // 5-7. edge pipeline chunked; node sums -> A1; EC2 stats accumulate
    //      (chunk 0 initializes PSTATS rows with accum=0 -- fixes the stats
    //       pollution from the previous gemm's leftover partials)
    for (int c = 0; c < NCHUNK; ++c) {
        const unsigned short* BFc = A0v + (size_t)c * CROWS_N * 512;
        gemm(stream, BFc, 512, 512, nullptr, 0, 0, WTpq, 512, 0, PQc, CROWS_N, 1024,
             nullptr, 0, nullptr, 0);
        hipLaunchKernelGGL(edge_gather_k, dim3((CROWS_E * 128 + 255) / 256), dim3(256),
                           0, stream, PQc, m1_b1, EC1);
        gemm(stream, EC1, 512, 512, nullptr, 0, 0, WTm1b, 512, 0, EC2, CROWS_E, 512,
             m1_b2, 2, PSTATS, (c > 0) ? 1 : 0);
        hipLaunchKernelGGL(edge_agg_k, dim3((CB * Vv * Tt * 128 + 255) / 256), dim3(256),
                           0, stream, EC2, A1v, c * CB);
    }
    // FOLD m1 BN (act=0, premul=1/3) into m2a weights; fused finalize
    fold_bn2(stream, PSTATS, 384, m1_g, m1_bb, (float)EROW, 1.f / 3.f,
             WTm2a, 512, 0, m2_w1, m2_b1, BIASF);

    // 8. m2 MLP (m2a consumes folded BN)
    gemm(stream, A1v, 512, 512, nullptr, 0, 0, WTm2a, 512, 0, A2v, NROW, 512,
         BIASF, 2, nullptr, 0);
    gemm(stream, A2v, 512, 512, nullptr, 0, 0, WTm2b, 512, 0, A1v, NROW, 512,
         m2_b2, 2, PSTATS, 0);
    fold_bn2(stream, PSTATS, 512, m2_g, m2_bb, (float)NROW, 1.f,
             WTt1a, 1024, 0, t1_w1, t1_b1, BIASF + 512);

    // 9. t1 MLP on cat(n2_raw, BF)
    gemm(stream, A1v, 512, 512, A0v, 512, 512, WTt1a, 1024, 0, A2v, NROW, 512,
         BIASF + 512, 2, nullptr, 0);
    gemm(stream, A2v, 512, 512, nullptr, 0, 0, WTt1b, 512, 0, A1v, NROW, 512,
         t1_b2, 2, PSTATS, 0);
    fold_bn2(stream, PSTATS, 512, t1_g, t1_bb, (float)NROW, 1.f,
             WTps1, 512, 0, ps_w1, nullptr, BIASF + 1024);

    // 10. ps (ps1 consumes folded BN; stats = pre-BN linear output as in ref)
    gemm(stream, A1v, 512, 512, nullptr, 0, 0, WTps1, 512, 0, A2v, NROW, 512,
         BIASF + 1024, 0, PSTATS, 0);
    bn_fused(stream, A2v, NROW, 512, PSTATS, 512, ps_g1, ps_b1,
             (float)NROW, 1.f, 1);

    gemm(stream, A2v, 512, 512, nullptr, 0, 0, WTps2, 512, 0, A0v, NROW, 512,
         nullptr, 0, PSTATS, 0);
    bn_fused(stream, A0v, NROW, 512, PSTATS, 512, ps_g2, ps_b2,
             (float)NROW, 1.f, 1);                                    // p_final in A0

    // 11. tb1 split-K=8 (A0 viewed [2048 x 8192]); partials; combine -> A1
    {
        dim3 g((512 / 128) * (2048 / 128), 1, 8);
        hipLaunchKernelGGL(gemm_bf16, g, dim3(256), 0, stream,
                           A0v, 8192, 8192, (const unsigned short*)nullptr, 0, 0,
                           WTtb1, 8192, 0, A1v, 2048, 512,
                           (const float*)nullptr, 0, (float*)nullptr, 0, Ppart, 1024);
        hipLaunchKernelGGL(combine_k, dim3(1, 2048 / 8), dim3(256), 0, stream,
                           (const float4*)Ppart, 8, 2048, A1v, PSTATS, 0);
    }
    bn_fused(stream, A1v, Bb * Vv, 512, PSTATS, 2048 / 8, tb_g1, tb_b1,
             (float)(Bb * Vv), 1.f, 1);

    gemm(stream, A1v, 512, 512, nullptr, 0, 0, WTtb2, 512, 0, A2v, Bb * Vv, 512,
         nullptr, 0, PSTATS, 0);
    bn_fused(stream, A2v, Bb * Vv, 512, PSTATS, (Bb * Vv / 128) * 2, tb_g2, tb_b2,
             (float)(Bb * Vv), 1.f, 1);                               // q2 in A2

    // 12. feat mean -> A0 (512x512)
    hipLaunchKernelGGL(feat_mean_k, dim3((Bb * 128 + 255) / 256), dim3(256), 0, stream,
                       A2v, A0v);

    // 13. classifier (no BN)
    gemm(stream, A0v, 512, 512, nullptr, 0, 0, WTcl1, 512, 0, A1v, Bb, 512,
         cl_b1, 1, nullptr, 0);
    gemm(stream, A1v, 512, 512, nullptr, 0, 0, WTcl2, 512, 0, A2v, Bb, 512,
         cl_b2, 1, nullptr, 0);
    hipLaunchKernelGGL(final_gemm_k, dim3(Bb / 4), dim3(256), 0, stream,
                       A2v, cl_w3, cl_b3, out);

    // 14. labels
    hipLaunchKernelGGL(copy_labels_k, dim3((Bb + 255) / 256), dim3(256), 0, stream,
                       vlabel, out + (size_t)Bb * NCc);
}

// Round 12
// 1274.052 us; speedup vs baseline: 1.0968x; 1.0968x over previous
//
#include <hip/hip_runtime.h>
#include <math.h>

#define EPS_ 1e-5f

static constexpr int Bb = 512, Vv = 4, Tt = 16, Dd = 512, NCc = 174;
static constexpr int NROW = Bb * Vv * Tt;      // 32768
static constexpr int EROW = Bb * 12 * Tt;      // 98304
static constexpr int CB = 128;                 // batches per edge chunk
static constexpr int NCHUNK = Bb / CB;         // 4
static constexpr int CROWS_N = CB * Vv * Tt;   // 8192
static constexpr int CROWS_E = CB * 12 * Tt;   // 24576

__constant__ int d_SEND[12] = {0,0,0,1,1,1,2,2,2,3,3,3};
__constant__ int d_RECV[12] = {1,2,3,0,2,3,0,1,3,0,1,2};
__constant__ int d_EOFV[4][3] = {{3,6,9},{0,7,10},{1,4,11},{2,5,8}};

typedef float f32x4 __attribute__((ext_vector_type(4)));
typedef short s16x8 __attribute__((ext_vector_type(8)));

static __device__ __forceinline__ float b2f(unsigned short u) {
    union { unsigned int i; float f; } x; x.i = ((unsigned int)u) << 16; return x.f;
}
static __device__ __forceinline__ unsigned short f2b(float f) {
    union { float f; unsigned int i; } x; x.f = f;
    unsigned int r = (x.i + 0x7fffu + ((x.i >> 16) & 1u)) >> 16;
    return (unsigned short)r;
}
static __device__ __forceinline__ float act_f(float v, int act) {
    if (act == 1) return fmaxf(v, 0.f);
    if (act == 2) return (v > 0.f) ? v : (__expf(v) - 1.f);
    return v;
}

#define GL2LDS(g, l) __builtin_amdgcn_global_load_lds(                     \
    (__attribute__((address_space(1))) void*)(g),                          \
    (__attribute__((address_space(3))) void*)(l), 16, 0, 0)

#define CS_STRIDE 136   // shorts per epilogue LDS row (128 + 8 pad), 16B aligned

// ================= MFMA bf16 GEMM (unchanged from round 10) ================
__global__ __launch_bounds__(256) void gemm_bf16(
    const unsigned short* __restrict__ A0, int Ka0, int K0,
    const unsigned short* __restrict__ A1, int Ka1, int K1,
    const unsigned short* __restrict__ WT, int Kw, int wtoff,
    unsigned short* __restrict__ C, int M, int N,
    const float* __restrict__ bias, int act,
    float* __restrict__ pstats, int accum,
    float* __restrict__ Cpart, int Ksl)
{
    __shared__ __align__(16) unsigned short SMEM[24576];
    int tid = threadIdx.x;
    int lane = tid & 63, wave = tid >> 6;
    int wr = wave >> 1, wc = wave & 1;
    int g = lane >> 4, r16 = lane & 15;

    int nct = N >> 7, nrt = M >> 7;
    int id = blockIdx.x, bx, by;
    if ((nrt & 7) == 0) {
        int grp = id / (nct * 8);
        int rem = id - grp * nct * 8;
        by = grp * 8 + (rem & 7);
        bx = rem >> 3;
    } else { bx = id % nct; by = id / nct; }
    int rowBase = by * 128;
    int colBase = bx * 128;
    int koff = blockIdx.z * Ksl;

    int u2 = lane >> 3;
    int q  = (lane & 7) ^ u2;
    int srow = wave * 32 + u2 * 2 + (q >> 2);
    int scol = (q & 3) * 8;
    const unsigned short* wrow  = WT + (size_t)(colBase + srow) * Kw + wtoff + scol;
    const unsigned short* wrow2 = WT + (size_t)(colBase + srow + 16) * Kw + wtoff + scol;

    f32x4 acc[4][4];
#pragma unroll
    for (int i = 0; i < 4; ++i)
#pragma unroll
        for (int j = 0; j < 4; ++j) acc[i][j] = (f32x4){0.f, 0.f, 0.f, 0.f};

#define STAGE_(kg_, SL_) do {                                                   \
        int kg = (kg_);                                                         \
        const unsigned short* Ap; int lda; int kc;                              \
        if (kg < K0) { Ap = A0; lda = Ka0; kc = kg; }                           \
        else         { Ap = A1; lda = Ka1; kc = kg - K0; }                      \
        const unsigned short* ga = Ap + (size_t)(rowBase + srow) * lda + kc + scol; \
        GL2LDS(ga, (SL_) + wave * 1024);                                        \
        GL2LDS(ga + (size_t)16 * lda, (SL_) + wave * 1024 + 512);               \
        GL2LDS(wrow + kg, (SL_) + 4096 + wave * 1024);                          \
        GL2LDS(wrow2 + kg, (SL_) + 4096 + wave * 1024 + 512);                   \
    } while (0)

    int nt = Ksl >> 5;
    STAGE_(koff, SMEM);
    if (nt > 1) STAGE_(koff + 32, SMEM + 8192);
    int cur = 0;
    int rh  = r16 >> 1;
    int sw8 = (((((r16 & 1) << 2) | g) ^ rh)) << 3;
    for (int t = 0; t < nt; ++t) {
        if (t + 1 < nt) asm volatile("s_waitcnt vmcnt(4)" ::: "memory");
        else            asm volatile("s_waitcnt vmcnt(0)" ::: "memory");
        __builtin_amdgcn_s_barrier();
        __builtin_amdgcn_sched_barrier(0);
        if (t + 2 < nt) {
            int nx = cur + 2; if (nx >= 3) nx -= 3;
            STAGE_(koff + (t + 2) * 32, SMEM + nx * 8192);
        }
        unsigned short* SA = SMEM + cur * 8192;
        unsigned short* SB = SA + 4096;
        s16x8 xf[4], wf[4];
#pragma unroll
        for (int j = 0; j < 4; ++j)
            xf[j] = *(const s16x8*)(SA + (wr * 32 + j * 8 + rh) * 64 + sw8);
#pragma unroll
        for (int i = 0; i < 4; ++i)
            wf[i] = *(const s16x8*)(SB + (wc * 32 + i * 8 + rh) * 64 + sw8);
#pragma unroll
        for (int i = 0; i < 4; ++i)
#pragma unroll
            for (int j = 0; j < 4; ++j)
                acc[i][j] = __builtin_amdgcn_mfma_f32_16x16x32_bf16(
                    wf[i], xf[j], acc[i][j], 0, 0, 0);
        cur = (cur == 2) ? 0 : cur + 1;
    }
#undef STAGE_
    __syncthreads();

    if (Cpart) {
#pragma unroll
        for (int j = 0; j < 4; ++j) {
            int row = rowBase + wr * 64 + j * 16 + r16;
#pragma unroll
            for (int i = 0; i < 4; ++i) {
                int col0 = colBase + wc * 64 + i * 16 + g * 4;
                float4 v = make_float4(acc[i][j][0], acc[i][j][1],
                                       acc[i][j][2], acc[i][j][3]);
                *(float4*)&Cpart[((size_t)blockIdx.z * M + row) * N + col0] = v;
            }
        }
        return;
    }

#pragma unroll
    for (int i = 0; i < 4; ++i) {
        int lc0 = wc * 64 + i * 16 + g * 4;
        float4 b4 = bias ? *(const float4*)(bias + colBase + lc0)
                         : make_float4(0.f, 0.f, 0.f, 0.f);
        float s[4] = {0.f, 0.f, 0.f, 0.f}, q2[4] = {0.f, 0.f, 0.f, 0.f};
#pragma unroll
        for (int j = 0; j < 4; ++j) {
            int lr = wr * 64 + j * 16 + r16;
            float v0 = act_f(acc[i][j][0] + b4.x, act);
            float v1 = act_f(acc[i][j][1] + b4.y, act);
            float v2 = act_f(acc[i][j][2] + b4.z, act);
            float v3 = act_f(acc[i][j][3] + b4.w, act);
            *(ushort4*)&SMEM[lr * CS_STRIDE + lc0] =
                make_ushort4(f2b(v0), f2b(v1), f2b(v2), f2b(v3));
            s[0] += v0; s[1] += v1; s[2] += v2; s[3] += v3;
            q2[0] += v0 * v0; q2[1] += v1 * v1; q2[2] += v2 * v2; q2[3] += v3 * v3;
        }
        if (pstats) {
#pragma unroll
            for (int p = 0; p < 4; ++p) {
#pragma unroll
                for (int d = 1; d < 16; d <<= 1) {
                    s[p] += __shfl_xor(s[p], d);
                    q2[p] += __shfl_xor(q2[p], d);
                }
            }
            if (r16 == 0) {
                float* pr = pstats + ((size_t)(by * 2 + wr)) * 1024 + colBase + lc0;
                float4 s4 = make_float4(s[0], s[1], s[2], s[3]);
                float4 q4 = make_float4(q2[0], q2[1], q2[2], q2[3]);
                if (accum) {
                    float4 o = *(float4*)pr;
                    s4.x += o.x; s4.y += o.y; s4.z += o.z; s4.w += o.w;
                    float4 o2 = *(float4*)(pr + 512);
                    q4.x += o2.x; q4.y += o2.y; q4.z += o2.z; q4.w += o2.w;
                }
                *(float4*)pr = s4;
                *(float4*)(pr + 512) = q4;
            }
        }
    }
    __syncthreads();
    {
        int qd = tid & 3;
        int rr = tid >> 2;
#pragma unroll
        for (int pass = 0; pass < 2; ++pass) {
            int lr = pass * 64 + rr;
            size_t grow = (size_t)(rowBase + lr) * N + colBase;
#pragma unroll
            for (int u = 0; u < 4; ++u) {
                int cofs = u * 32 + qd * 8;
                uint4 v = *(const uint4*)(SMEM + lr * CS_STRIDE + cofs);
                *(uint4*)&C[grow + cofs] = v;
            }
        }
    }
}

// ---- stats partial reduction: slot[t] = sum_r P[r][t], t in [0,1024) -------
// grid 16 x 256: block covers 64 columns; 4 row-segments + LDS reduce
__global__ __launch_bounds__(256) void finalize_stats_k(
    const float* __restrict__ P, int nrows, float* __restrict__ slot)
{
    __shared__ float red[256];
    int lane = threadIdx.x & 63;
    int seg  = threadIdx.x >> 6;          // 0..3
    int col  = blockIdx.x * 64 + lane;
    float s = 0.f;
    for (int r = seg; r < nrows; r += 4)
        s += P[(size_t)r * 1024 + col];
    red[threadIdx.x] = s;
    __syncthreads();
    if (seg == 0)
        slot[col] = red[lane] + red[64 + lane] + red[128 + lane] + red[192 + lane];
}

// ---- FUSED stats-finalize + BN apply ---------------------------------------
__global__ __launch_bounds__(256) void bn_fused_k(
    unsigned short* __restrict__ X, int C, int rps,
    const float* __restrict__ P, int nrows,
    const float* __restrict__ gm, const float* __restrict__ bt,
    float inv_cnt, float premul, int act)
{
    __shared__ float red[512];
    __shared__ float sc_s[64], sh_s[64];
    int cg = blockIdx.x;
    int lane = threadIdx.x & 63;
    int seg  = threadIdx.x >> 6;
    int c = cg * 64 + lane;
    float s = 0.f, q = 0.f;
    for (int r = seg; r < nrows; r += 4) {
        s += P[(size_t)r * 1024 + c];
        q += P[(size_t)r * 1024 + 512 + c];
    }
    red[threadIdx.x] = s; red[256 + threadIdx.x] = q;
    __syncthreads();
    if (seg == 0) {
        float S = red[lane] + red[64 + lane] + red[128 + lane] + red[192 + lane];
        float Q = red[256 + lane] + red[320 + lane] + red[384 + lane] + red[448 + lane];
        float mean = S * inv_cnt;
        float var = fmaxf(Q * inv_cnt - mean * mean, 0.f);
        float sc = gm[c] * rsqrtf(var + EPS_);
        sc_s[lane] = sc * premul;
        sh_s[lane] = bt[c] - mean * sc;
    }
    __syncthreads();
    int r0 = blockIdx.y * rps;
    int c4 = threadIdx.x & 15;
    int ro = threadIdx.x >> 4;
    for (int r = r0 + ro; r < r0 + rps; r += 16) {
        ushort4* px = (ushort4*)&X[(size_t)r * C + cg * 64] + c4;
        ushort4 x = *px;
        unsigned short o[4] = {x.x, x.y, x.z, x.w};
#pragma unroll
        for (int e = 0; e < 4; ++e) {
            float v = b2f(o[e]) * sc_s[c4 * 4 + e] + sh_s[c4 * 4 + e];
            o[e] = f2b(act_f(v, act));
        }
        *px = make_ushort4(o[0], o[1], o[2], o[3]);
    }
}

// ---- BN fold into consuming gemm (round-10 geometry, reads finalized slot) -
// blocks 0..1023: WT[n][kof+k] *= sc[k]*premul (coalesced RMW)
// blocks 1024..1031: bias_out[n] = bias_in[n] + sum_k sh[k]*Wsrc[k*512+n]
//   8 blocks x 64 cols, 4-way k-split (128 iters/thread) + LDS reduce.
__global__ __launch_bounds__(256) void fold_bn_k(
    const float* __restrict__ slot, const float* __restrict__ gm,
    const float* __restrict__ bt, float inv_cnt, float premul,
    unsigned short* __restrict__ WT, int Kw, int kof,
    const float* __restrict__ Wsrc, const float* __restrict__ bias_in,
    float* __restrict__ bias_out)
{
    int blk = blockIdx.x;
    if (blk < 1024) {
        int i = blk * 256 + threadIdx.x;
        int n = i >> 9, k = i & 511;
        float mean = slot[k] * inv_cnt;
        float var = fmaxf(slot[512 + k] * inv_cnt - mean * mean, 0.f);
        float sc = gm[k] * rsqrtf(var + EPS_) * premul;
        unsigned short* p = &WT[(size_t)n * Kw + kof + k];
        *p = f2b(b2f(*p) * sc);
    } else {
        __shared__ float red[256];
        int blk2 = blk - 1024;            // 0..7
        int lane = threadIdx.x & 63;
        int seg  = threadIdx.x >> 6;      // 0..3
        int n = blk2 * 64 + lane;
        float acc = 0.f;
        int k0 = seg * 128;
#pragma unroll 4
        for (int k = k0; k < k0 + 128; ++k) {
            float mean = slot[k] * inv_cnt;
            float var = fmaxf(slot[512 + k] * inv_cnt - mean * mean, 0.f);
            float sc = gm[k] * rsqrtf(var + EPS_);
            float sh = bt[k] - mean * sc;
            acc += sh * Wsrc[(size_t)k * 512 + n];
        }
        red[threadIdx.x] = acc;
        __syncthreads();
        if (seg == 0)
            bias_out[n] = (bias_in ? bias_in[n] : 0.f)
                        + red[lane] + red[64 + lane]
                        + red[128 + lane] + red[192 + lane];
    }
}

// ---- split-K combine, parallel + vectorized; stats -> partials -------------
__global__ __launch_bounds__(256) void combine_k(
    const float4* __restrict__ P, int S, int M,
    unsigned short* __restrict__ C, float* __restrict__ pstats, int act)
{
    int col4 = threadIdx.x & 127;
    int rh = threadIdx.x >> 7;
    int rb = blockIdx.y * 8;
    float4 s4 = make_float4(0.f, 0.f, 0.f, 0.f);
    float4 q4 = make_float4(0.f, 0.f, 0.f, 0.f);
#pragma unroll
    for (int i = 0; i < 4; ++i) {
        int row = rb + rh + 2 * i;
        float4 v = make_float4(0.f, 0.f, 0.f, 0.f);
#pragma unroll
        for (int z = 0; z < 8; ++z) {
            float4 p = P[((size_t)z * M + row) * 128 + col4];
            v.x += p.x; v.y += p.y; v.z += p.z; v.w += p.w;
        }
        v.x = act_f(v.x, act); v.y = act_f(v.y, act);
        v.z = act_f(v.z, act); v.w = act_f(v.w, act);
        ((ushort4*)C)[(size_t)row * 128 + col4] =
            make_ushort4(f2b(v.x), f2b(v.y), f2b(v.z), f2b(v.w));
        s4.x += v.x; s4.y += v.y; s4.z += v.z; s4.w += v.w;
        q4.x += v.x * v.x; q4.y += v.y * v.y; q4.z += v.z * v.z; q4.w += v.w * v.w;
    }
    __shared__ float4 sb[256], qb[256];
    sb[threadIdx.x] = s4; qb[threadIdx.x] = q4;
    __syncthreads();
    if (threadIdx.x < 128) {
        float4 a = sb[threadIdx.x], b = sb[threadIdx.x + 128];
        float4 c = qb[threadIdx.x], d = qb[threadIdx.x + 128];
        int col = threadIdx.x * 4;
        float* pr = pstats + (size_t)blockIdx.y * 1024 + col;
        *(float4*)pr = make_float4(a.x + b.x, a.y + b.y, a.z + b.z, a.w + b.w);
        *(float4*)(pr + 512) = make_float4(c.x + d.x, c.y + d.y, c.z + d.z, c.w + d.w);
    }
}

// ---- batched weight convert+transpose, LDS-tiled ---------------------------
#define NTD 13
struct TBatch {
    const float* src[NTD];
    unsigned short* dst[NTD];
    int K[NTD];
    int tbase[NTD + 1];
};
__global__ __launch_bounds__(256) void transpose_batch_k(TBatch tb)
{
    int id = blockIdx.x;
    int d = 0;
#pragma unroll
    for (int j = 0; j < NTD; ++j) if (id >= tb.tbase[j + 1]) d = j + 1;
    int rel = id - tb.tbase[d];
    int kt = rel >> 3, ntl = rel & 7;
    int k0 = kt * 64, n0 = ntl * 64;
    const float* S = tb.src[d];
    unsigned short* D = tb.dst[d];
    int K = tb.K[d];
    __shared__ unsigned short L[64][68];
    int c = threadIdx.x & 63;
    int r = threadIdx.x >> 6;
#pragma unroll
    for (int p = 0; p < 16; ++p) {
        int kk = r + p * 4;
        L[kk][c] = f2b(S[(size_t)(k0 + kk) * 512 + n0 + c]);
    }
    __syncthreads();
#pragma unroll
    for (int p = 0; p < 16; ++p) {
        int nn = r + p * 4;
        D[(size_t)(n0 + nn) * K + k0 + c] = L[c][nn];
    }
}

// fused P/Q transpose for m1_w1 [1024,512], LDS-tiled (two 512x512 halves)
__global__ __launch_bounds__(256) void transpose_pq_k(
    const float* __restrict__ W, unsigned short* __restrict__ WT)
{
    int id = blockIdx.x;
    int kt = id >> 4, ntl = id & 15;
    int k0 = kt * 64, n0 = ntl * 64;
    __shared__ unsigned short L[64][68];
    int c = threadIdx.x & 63;
    int r = threadIdx.x >> 6;
    int nb = n0 + c;
    const float* S = (n0 < 512) ? (W + nb) : (W + (size_t)512 * 512 + (nb - 512));
#pragma unroll
    for (int p = 0; p < 16; ++p) {
        int kk = r + p * 4;
        L[kk][c] = f2b(S[(size_t)(k0 + kk) * 512]);
    }
    __syncthreads();
#pragma unroll
    for (int p = 0; p < 16; ++p) {
        int nn = r + p * 4;
        WT[(size_t)(n0 + nn) * 512 + k0 + c] = L[c][nn];
    }
}

// ---- column stats over Y1 [NROW, 256] bf16 -> PSTATS rows 0..255 -----------
__global__ __launch_bounds__(256) void colstats_k(
    const unsigned short* __restrict__ X, float* __restrict__ P)
{
    __shared__ float sb[256][4], qb[256][4];
    int c4 = threadIdx.x & 63;
    int seg = threadIdx.x >> 6;
    int r0 = blockIdx.x * 128;
    float s[4] = {0.f, 0.f, 0.f, 0.f}, q[4] = {0.f, 0.f, 0.f, 0.f};
    for (int r = r0 + seg; r < r0 + 128; r += 4) {
        ushort4 x = ((const ushort4*)X)[(size_t)r * 64 + c4];
        float v0 = b2f(x.x), v1 = b2f(x.y), v2 = b2f(x.z), v3 = b2f(x.w);
        s[0] += v0; s[1] += v1; s[2] += v2; s[3] += v3;
        q[0] += v0 * v0; q[1] += v1 * v1; q[2] += v2 * v2; q[3] += v3 * v3;
    }
#pragma unroll
    for (int e = 0; e < 4; ++e) { sb[threadIdx.x][e] = s[e]; qb[threadIdx.x][e] = q[e]; }
    __syncthreads();
    if (threadIdx.x < 64) {
        int c = threadIdx.x;
        float4 S, Q;
        S.x = sb[c][0] + sb[c + 64][0] + sb[c + 128][0] + sb[c + 192][0];
        S.y = sb[c][1] + sb[c + 64][1] + sb[c + 128][1] + sb[c + 192][1];
        S.z = sb[c][2] + sb[c + 64][2] + sb[c + 128][2] + sb[c + 192][2];
        S.w = sb[c][3] + sb[c + 64][3] + sb[c + 128][3] + sb[c + 192][3];
        Q.x = qb[c][0] + qb[c + 64][0] + qb[c + 128][0] + qb[c + 192][0];
        Q.y = qb[c][1] + qb[c + 64][1] + qb[c + 128][1] + qb[c + 192][1];
        Q.z = qb[c][2] + qb[c + 64][2] + qb[c + 128][2] + qb[c + 192][2];
        Q.w = qb[c][3] + qb[c + 64][3] + qb[c + 128][3] + qb[c + 192][3];
        *(float4*)&P[(size_t)blockIdx.x * 1024 + c * 4] = S;
        *(float4*)&P[(size_t)blockIdx.x * 1024 + 512 + c * 4] = Q;
    }
}

// ---------------- misc ------------------------------------------------------
// merged input builders: blocks [0,512) build X0, [512,8704) build CE
__global__ __launch_bounds__(256) void build_inputs_k(
    const float* __restrict__ box, float* __restrict__ X0,
    const int* __restrict__ cats, const float* __restrict__ emb,
    unsigned short* __restrict__ CE)
{
    if (blockIdx.x < 512) {
        int i = blockIdx.x * 256 + threadIdx.x;      // NROW*4 = 131072
        int c = i & 3; int r = i >> 2;
        int t = r & 15; int bv = r >> 4; int v = bv & 3; int b = bv >> 2;
        X0[i] = box[(((size_t)b * Tt + t) * Vv + v) * 4 + c];
    } else {
        int i = (blockIdx.x - 512) * 256 + threadIdx.x;   // NROW*64
        int c4 = i & 63; int r = i >> 6;
        int t = r & 15; int bv = r >> 4; int v = bv & 3; int b = bv >> 2;
        int cat = cats[((size_t)b * Tt + t) * Vv + v];
        unsigned short o[4];
#pragma unroll
        for (int e = 0; e < 4; ++e)
            o[e] = (cat == 0) ? 0 : f2b(emb[cat * 256 + c4 * 4 + e]);
        ((ushort4*)CE)[(size_t)r * 64 + c4] = make_ushort4(o[0], o[1], o[2], o[3]);
    }
}

__global__ __launch_bounds__(256) void smallk_gemm_k(
    const float* __restrict__ X0, const float* __restrict__ W4,
    unsigned short* __restrict__ Y1)
{
    int i = blockIdx.x * 256 + threadIdx.x;
    if (i >= NROW * 64) return;
    int n4 = i & 63; int m = i >> 6;
    float4 x = *(const float4*)(X0 + m * 4);
    unsigned short o[4];
#pragma unroll
    for (int e = 0; e < 4; ++e) {
        int n = n4 * 4 + e;
        float v = x.x * W4[n] + x.y * W4[256 + n] + x.z * W4[512 + n] + x.w * W4[768 + n];
        o[e] = f2b(v);
    }
    ((ushort4*)Y1)[(size_t)m * 64 + n4] = make_ushort4(o[0], o[1], o[2], o[3]);
}

__global__ __launch_bounds__(256) void edge_gather_k(
    const unsigned short* __restrict__ PQ,
    const float* __restrict__ b1, unsigned short* __restrict__ E)
{
    int i = blockIdx.x * 256 + threadIdx.x;
    if (i >= CROWS_E * 128) return;
    int c4 = i & 127; int m = i >> 7;
    int t = m & 15; int be = m >> 4; int e = be % 12; int brel = be / 12;
    int s = d_SEND[e], r = d_RECV[e];
    ushort4 p = ((const ushort4*)PQ)[(((size_t)brel * 4 + s) * 16 + t) * 256 + c4];
    ushort4 q = ((const ushort4*)PQ)[(((size_t)brel * 4 + r) * 16 + t) * 256 + 128 + c4];
    unsigned short pa[4] = {p.x, p.y, p.z, p.w}, qa[4] = {q.x, q.y, q.z, q.w}, o[4];
#pragma unroll
    for (int e2 = 0; e2 < 4; ++e2) {
        float v = b2f(pa[e2]) + b2f(qa[e2]) + b1[c4 * 4 + e2];
        o[e2] = f2b(act_f(v, 2));
    }
    ((ushort4*)E)[i] = make_ushort4(o[0], o[1], o[2], o[3]);
}

__global__ __launch_bounds__(256) void edge_agg_k(
    const unsigned short* __restrict__ E2c, unsigned short* __restrict__ nraw, int b0)
{
    int i = blockIdx.x * 256 + threadIdx.x;
    if (i >= CB * Vv * Tt * 128) return;
    int c4 = i & 127; int r = i >> 7;
    int t = r & 15; int r2 = r >> 4; int v = r2 & 3; int brel = r2 >> 2;
    float s[4] = {0.f, 0.f, 0.f, 0.f};
#pragma unroll
    for (int j = 0; j < 3; ++j) {
        int e = d_EOFV[v][j];
        ushort4 x = ((const ushort4*)E2c)[(((size_t)brel * 12 + e) * 16 + t) * 128 + c4];
        s[0] += b2f(x.x); s[1] += b2f(x.y); s[2] += b2f(x.z); s[3] += b2f(x.w);
    }
    ((ushort4*)nraw)[((((size_t)(b0 + brel)) * 4 + v) * 16 + t) * 128 + c4] =
        make_ushort4(f2b(s[0]), f2b(s[1]), f2b(s[2]), f2b(s[3]));
}

__global__ __launch_bounds__(256) void feat_mean_k(
    const unsigned short* __restrict__ q, unsigned short* __restrict__ feat)
{
    int i = blockIdx.x * 256 + threadIdx.x;
    if (i >= Bb * 128) return;
    int c4 = i & 127; int b = i >> 7;
    float s[4] = {0.f, 0.f, 0.f, 0.f};
#pragma unroll
    for (int v = 0; v < 4; ++v) {
        ushort4 x = ((const ushort4*)q)[(((size_t)b * 4 + v)) * 128 + c4];
        s[0] += b2f(x.x); s[1] += b2f(x.y); s[2] += b2f(x.z); s[3] += b2f(x.w);
    }
    ((ushort4*)feat)[(size_t)b * 128 + c4] = make_ushort4(
        f2b(0.25f * s[0]), f2b(0.25f * s[1]), f2b(0.25f * s[2]), f2b(0.25f * s[3]));
}

__global__ __launch_bounds__(256) void final_gemm_k(
    const unsigned short* __restrict__ H2, const float* __restrict__ W,
    const float* __restrict__ b, float* __restrict__ out)
{
    __shared__ float Ls[4 * 512];
    int m0 = blockIdx.x * 4;
    for (int i = threadIdx.x; i < 512; i += 256) {
        ushort4 x = ((const ushort4*)H2)[(size_t)m0 * 128 + i];
        *(float4*)&Ls[i * 4] = make_float4(b2f(x.x), b2f(x.y), b2f(x.z), b2f(x.w));
    }
    __syncthreads();
    int n = threadIdx.x;
    if (n >= NCc) return;
    float a0 = b[n], a1 = a0, a2 = a0, a3 = a0;
#pragma unroll 8
    for (int k = 0; k < 512; ++k) {
        float w = W[(size_t)k * NCc + n];
        a0 += Ls[k] * w;
        a1 += Ls[512 + k] * w;
        a2 += Ls[1024 + k] * w;
        a3 += Ls[1536 + k] * w;
    }
    out[(size_t)m0 * NCc + n] = a0;
    out[(size_t)(m0 + 1) * NCc + n] = a1;
    out[(size_t)(m0 + 2) * NCc + n] = a2;
    out[(size_t)(m0 + 3) * NCc + n] = a3;
}

__global__ __launch_bounds__(256) void copy_labels_k(
    const int* __restrict__ lab, float* __restrict__ out)
{
    int i = blockIdx.x * 256 + threadIdx.x;
    if (i < Bb) out[i] = (float)lab[i];
}

// ---------------- host-side helpers -----------------------------------------
static inline void gemm(hipStream_t s,
                        const unsigned short* A0, int Ka0, int K0,
                        const unsigned short* A1, int Ka1, int K1,
                        const unsigned short* WT, int Kw, int wtoff,
                        unsigned short* C, int M, int N,
                        const float* bias, int act, float* pstats, int accum)
{
    dim3 g((N / 128) * (M / 128), 1, 1);
    hipLaunchKernelGGL(gemm_bf16, g, dim3(256), 0, s,
                       A0, Ka0, K0, A1, Ka1, K1, WT, Kw, wtoff, C, M, N,
                       bias, act, pstats, accum, (float*)nullptr, K0 + K1);
}

static inline void bn_fused(hipStream_t s, unsigned short* X, int R, int C,
                            const float* P, int nrows, const float* gm,
                            const float* bt, float cnt, float premul, int act)
{
    int nslabs = (R >= 8192) ? 64 : 16;
    hipLaunchKernelGGL(bn_fused_k, dim3(C / 64, nslabs), dim3(256), 0, s,
                       X, C, R / nslabs, P, nrows, gm, bt, 1.f / cnt, premul, act);
}

static inline void fold_bn(hipStream_t s, const float* P, int nrows, float* slot,
                           const float* gm, const float* bt, float cnt,
                           float premul, unsigned short* WT, int Kw, int kof,
                           const float* Wsrc, const float* bias_in, float* bias_out)
{
    hipLaunchKernelGGL(finalize_stats_k, dim3(16), dim3(256), 0, s, P, nrows, slot);
    hipLaunchKernelGGL(fold_bn_k, dim3(1032), dim3(256), 0, s,
                       slot, gm, bt, 1.f / cnt, premul, WT, Kw, kof,
                       Wsrc, bias_in, bias_out);
}

extern "C" void kernel_launch(void* const* d_in, const int* in_sizes, int n_in,
                              void* d_out, int out_size, void* d_ws, size_t ws_size,
                              hipStream_t stream)
{
    const int*   box_cat = (const int*)  d_in[1];
    const float* box_in  = (const float*)d_in[2];
    const int*   vlabel  = (const int*)  d_in[4];
    const float* emb     = (const float*)d_in[5];
    const float* c2f_w1  = (const float*)d_in[6];
    const float* c2f_g1  = (const float*)d_in[7];
    const float* c2f_b1  = (const float*)d_in[8];
    const float* c2f_w2  = (const float*)d_in[9];
    const float* c2f_g2  = (const float*)d_in[10];
    const float* c2f_b2  = (const float*)d_in[11];
    const float* fus_w   = (const float*)d_in[12];
    const float* fus_g   = (const float*)d_in[13];
    const float* fus_b   = (const float*)d_in[14];
    const float* m1_w1   = (const float*)d_in[15];
    const float* m1_b1   = (const float*)d_in[16];
    const float* m1_w2   = (const float*)d_in[17];
    const float* m1_b2   = (const float*)d_in[18];
    const float* m1_g    = (const float*)d_in[19];
    const float* m1_bb   = (const float*)d_in[20];
    const float* m2_w1   = (const float*)d_in[21];
    const float* m2_b1   = (const float*)d_in[22];
    const float* m2_w2   = (const float*)d_in[23];
    const float* m2_b2   = (const float*)d_in[24];
    const float* m2_g    = (const float*)d_in[25];
    const float* m2_bb   = (const float*)d_in[26];
    const float* t1_w1   = (const float*)d_in[27];
    const float* t1_b1   = (const float*)d_in[28];
    const float* t1_w2   = (const float*)d_in[29];
    const float* t1_b2   = (const float*)d_in[30];
    const float* t1_g    = (const float*)d_in[31];
    const float* t1_bb   = (const float*)d_in[32];
    const float* ps_w1   = (const float*)d_in[33];
    const float* ps_g1   = (const float*)d_in[34];
    const float* ps_b1   = (const float*)d_in[35];
    const float* ps_w2   = (const float*)d_in[36];
    const float* ps_g2   = (const float*)d_in[37];
    const float* ps_b2   = (const float*)d_in[38];
    const float* tb_w1   = (const float*)d_in[39];
    const float* tb_g1   = (const float*)d_in[40];
    const float* tb_b1   = (const float*)d_in[41];
    const float* tb_w2   = (const float*)d_in[42];
    const float* tb_g2   = (const float*)d_in[43];
    const float* tb_b2   = (const float*)d_in[44];
    const float* cl_w1   = (const float*)d_in[45];
    const float* cl_b1   = (const float*)d_in[46];
    const float* cl_w2   = (const float*)d_in[47];
    const float* cl_b2   = (const float*)d_in[48];
    const float* cl_w3   = (const float*)d_in[49];
    const float* cl_b3   = (const float*)d_in[50];

    float* out = (float*)d_out;

    // ---------------- workspace layout (bytes) ------------------------------
    char* base = (char*)d_ws;
    const size_t SZ_ACT = (size_t)NROW * 512 * 2;       // 32 MB
    unsigned short* A0v = (unsigned short*)(base);
    unsigned short* A1v = (unsigned short*)(base + SZ_ACT);
    char* Sreg = base + 2 * SZ_ACT;                     // scratch region
    unsigned short* A2v = (unsigned short*)Sreg;
    unsigned short* CE  = (unsigned short*)Sreg;
    unsigned short* Y1  = (unsigned short*)(Sreg + (size_t)NROW * 256 * 2);
    unsigned short* PQc = (unsigned short*)Sreg;
    unsigned short* EC1 = (unsigned short*)(Sreg + (size_t)CROWS_N * 1024 * 2);
    unsigned short* EC2 = (unsigned short*)(Sreg + (size_t)CROWS_N * 1024 * 2
                                                 + (size_t)CROWS_E * 512 * 2);
    float* Ppart = (float*)Sreg;
    char* wtb = Sreg + (size_t)CROWS_N * 1024 * 2 + 2 * (size_t)CROWS_E * 512 * 2;
    unsigned short* wtp = (unsigned short*)wtb;
    size_t wo = 0;
    auto alloc_wt = [&](int K) { unsigned short* p = wtp + wo; wo += (size_t)K * 512; return p; };
    unsigned short* WTc2f2 = alloc_wt(256);
    unsigned short* WTfus  = alloc_wt(768);
    unsigned short* WTpq   = alloc_wt(1024);
    unsigned short* WTm1b  = alloc_wt(512);
    unsigned short* WTm2a  = alloc_wt(512);
    unsigned short* WTm2b  = alloc_wt(512);
    unsigned short* WTt1a  = alloc_wt(1024);
    unsigned short* WTt1b  = alloc_wt(512);
    unsigned short* WTps1  = alloc_wt(512);
    unsigned short* WTps2  = alloc_wt(512);
    unsigned short* WTtb1  = alloc_wt(8192);
    unsigned short* WTtb2  = alloc_wt(512);
    unsigned short* WTcl1  = alloc_wt(512);
    unsigned short* WTcl2  = alloc_wt(512);
    float* X0f    = (float*)(wtp + wo);
    float* STATS  = X0f + (size_t)NROW * 4;   // slot scratch for folds
    float* PSTATS = STATS + 10 * 1024;        // 512 rows x 1024 f32 = 2 MB
    float* BIASF  = PSTATS + 512 * 1024;      // 3 x 512 f32 folded biases

    // 0. weight prep (no zeroing: PSTATS rows initialized by '=' writes;
    //    m1b chunk 0 uses accum=0 -- keeps the round-11 stats-pollution fix)
    {
        TBatch tb;
        const float* srcs[NTD] = {c2f_w2, fus_w, m1_w2, m2_w1, m2_w2, t1_w1, t1_w2,
                                  ps_w1, ps_w2, tb_w1, tb_w2, cl_w1, cl_w2};
        unsigned short* dsts[NTD] = {WTc2f2, WTfus, WTm1b, WTm2a, WTm2b, WTt1a, WTt1b,
                                     WTps1, WTps2, WTtb1, WTtb2, WTcl1, WTcl2};
        int Ks[NTD] = {256, 768, 512, 512, 512, 1024, 512, 512, 512, 8192, 512, 512, 512};
        int acc = 0;
        for (int i = 0; i < NTD; ++i) {
            tb.src[i] = srcs[i]; tb.dst[i] = dsts[i]; tb.K[i] = Ks[i];
            tb.tbase[i] = acc; acc += (Ks[i] / 64) * 8;
        }
        tb.tbase[NTD] = acc;
        hipLaunchKernelGGL(transpose_batch_k, dim3((unsigned)acc), dim3(256), 0,
                           stream, tb);
    }
    hipLaunchKernelGGL(transpose_pq_k, dim3(128), dim3(256), 0, stream, m1_w1, WTpq);

    // 1. inputs (merged builder)
    hipLaunchKernelGGL(build_inputs_k, dim3(512 + NROW * 64 / 256), dim3(256), 0,
                       stream, box_in, X0f, box_cat, emb, CE);

    // 2. c2f layer 1 (K=4 fp32) -> Y1 [NROW,256]; stats -> PSTATS; fused BN
    hipLaunchKernelGGL(smallk_gemm_k, dim3((NROW * 64 + 255) / 256), dim3(256), 0,
                       stream, X0f, c2f_w1, Y1);
    hipLaunchKernelGGL(colstats_k, dim3(NROW / 128), dim3(256), 0, stream, Y1, PSTATS);
    bn_fused(stream, Y1, NROW, 256, PSTATS, NROW / 128, c2f_g1, c2f_b1,
             (float)NROW, 1.f, 1);

    // 3. c2f layer 2 -> A1 (stats fused); fused BN+ReLU
    gemm(stream, Y1, 256, 256, nullptr, 0, 0, WTc2f2, 256, 0, A1v, NROW, 512,
         nullptr, 0, PSTATS, 0);
    bn_fused(stream, A1v, NROW, 512, PSTATS, 512, c2f_g2, c2f_b2,
             (float)NROW, 1.f, 1);

    // 4. fusion dual-K -> A0 (BF); fused BN+ReLU
    gemm(stream, A1v, 512, 512, CE, 256, 256, WTfus, 768, 0, A0v, NROW, 512,
         nullptr, 0, PSTATS, 0);
    bn_fused(stream, A0v, NROW, 512, PSTATS, 512, fus_g, fus_b,
             (float)NROW, 1.f, 1);                                    // BF in A0

    // 5-7. edge pipeline chunked; node sums -> A1; chunk 0 initializes PSTATS
    for (int c = 0; c < NCHUNK; ++c) {
        const unsigned short* BFc = A0v + (size_t)c * CROWS_N * 512;
        gemm(stream, BFc, 512, 512, nullptr, 0, 0, WTpq, 512, 0, PQc, CROWS_N, 1024,
             nullptr, 0, nullptr, 0);
        hipLaunchKernelGGL(edge_gather_k, dim3((CROWS_E * 128 + 255) / 256), dim3(256),
                           0, stream, PQc, m1_b1, EC1);
        gemm(stream, EC1, 512, 512, nullptr, 0, 0, WTm1b, 512, 0, EC2, CROWS_E, 512,
             m1_b2, 2, PSTATS, (c > 0) ? 1 : 0);
        hipLaunchKernelGGL(edge_agg_k, dim3((CB * Vv * Tt * 128 + 255) / 256), dim3(256),
                           0, stream, EC2, A1v, c * CB);
    }
    // FOLD m1 BN (act=0, premul=1/3) into m2a weights (finalize + 1032-blk fold)
    fold_bn(stream, PSTATS, 384, STATS, m1_g, m1_bb, (float)EROW, 1.f / 3.f,
            WTm2a, 512, 0, m2_w1, m2_b1, BIASF);

    // 8. m2 MLP (m2a consumes folded BN)
    gemm(stream, A1v, 512, 512, nullptr, 0, 0, WTm2a, 512, 0, A2v, NROW, 512,
         BIASF, 2, nullptr, 0);
    gemm(stream, A2v, 512, 512, nullptr, 0, 0, WTm2b, 512, 0, A1v, NROW, 512,
         m2_b2, 2, PSTATS, 0);
    fold_bn(stream, PSTATS, 512, STATS, m2_g, m2_bb, (float)NROW, 1.f,
            WTt1a, 1024, 0, t1_w1, t1_b1, BIASF + 512);

    // 9. t1 MLP on cat(n2_raw, BF)
    gemm(stream, A1v, 512, 512, A0v, 512, 512, WTt1a, 1024, 0, A2v, NROW, 512,
         BIASF + 512, 2, nullptr, 0);
    gemm(stream, A2v, 512, 512, nullptr, 0, 0, WTt1b, 512, 0, A1v, NROW, 512,
         t1_b2, 2, PSTATS, 0);
    fold_bn(stream, PSTATS, 512, STATS, t1_g, t1_bb, (float)NROW, 1.f,
            WTps1, 512, 0, ps_w1, nullptr, BIASF + 1024);

    // 10. ps (ps1 consumes folded BN; stats = pre-BN linear output as in ref)
    gemm(stream, A1v, 512, 512, nullptr, 0, 0, WTps1, 512, 0, A2v, NROW, 512,
         BIASF + 1024, 0, PSTATS, 0);
    bn_fused(stream, A2v, NROW, 512, PSTATS, 512, ps_g1, ps_b1,
             (float)NROW, 1.f, 1);

    gemm(stream, A2v, 512, 512, nullptr, 0, 0, WTps2, 512, 0, A0v, NROW, 512,
         nullptr, 0, PSTATS, 0);
    bn_fused(stream, A0v, NROW, 512, PSTATS, 512, ps_g2, ps_b2,
             (float)NROW, 1.f, 1);                                    // p_final in A0

    // 11. tb1 split-K=8 (A0 viewed [2048 x 8192]); partials; combine -> A1
    {
        dim3 g((512 / 128) * (2048 / 128), 1, 8);
        hipLaunchKernelGGL(gemm_bf16, g, dim3(256), 0, stream,
                           A0v, 8192, 8192, (const unsigned short*)nullptr, 0, 0,
                           WTtb1, 8192, 0, A1v, 2048, 512,
                           (const float*)nullptr, 0, (float*)nullptr, 0, Ppart, 1024);
        hipLaunchKernelGGL(combine_k, dim3(1, 2048 / 8), dim3(256), 0, stream,
                           (const float4*)Ppart, 8, 2048, A1v, PSTATS, 0);
    }
    bn_fused(stream, A1v, Bb * Vv, 512, PSTATS, 2048 / 8, tb_g1, tb_b1,
             (float)(Bb * Vv), 1.f, 1);

    gemm(stream, A1v, 512, 512, nullptr, 0, 0, WTtb2, 512, 0, A2v, Bb * Vv, 512,
         nullptr, 0, PSTATS, 0);
    bn_fused(stream, A2v, Bb * Vv, 512, PSTATS, (Bb * Vv / 128) * 2, tb_g2, tb_b2,
             (float)(Bb * Vv), 1.f, 1);                               // q2 in A2

    // 12. feat mean -> A0 (512x512)
    hipLaunchKernelGGL(feat_mean_k, dim3((Bb * 128 + 255) / 256), dim3(256), 0, stream,
                       A2v, A0v);

    // 13. classifier (no BN)
    gemm(stream, A0v, 512, 512, nullptr, 0, 0, WTcl1, 512, 0, A1v, Bb, 512,
         cl_b1, 1, nullptr, 0);
    gemm(stream, A1v, 512, 512, nullptr, 0, 0, WTcl2, 512, 0, A2v, Bb, 512,
         cl_b2, 1, nullptr, 0);
    hipLaunchKernelGGL(final_gemm_k, dim3(Bb / 4), dim3(256), 0, stream,
                       A2v, cl_w3, cl_b3, out);

    // 14. labels
    hipLaunchKernelGGL(copy_labels_k, dim3((Bb + 255) / 256), dim3(256), 0, stream,
                       vlabel, out + (size_t)Bb * NCc);
}

// Round 13
// 1252.676 us; speedup vs baseline: 1.1155x; 1.0171x over previous
//
#include <hip/hip_runtime.h>
#include <math.h>

#define EPS_ 1e-5f

static constexpr int Bb = 512, Vv = 4, Tt = 16, Dd = 512, NCc = 174;
static constexpr int NROW = Bb * Vv * Tt;      // 32768
static constexpr int EROW = Bb * 12 * Tt;      // 98304
static constexpr int CB = 128;                 // batches per edge chunk
static constexpr int NCHUNK = Bb / CB;         // 4
static constexpr int CROWS_N = CB * Vv * Tt;   // 8192
static constexpr int CROWS_E = CB * 12 * Tt;   // 24576

__constant__ int d_SEND[12] = {0,0,0,1,1,1,2,2,2,3,3,3};
__constant__ int d_RECV[12] = {1,2,3,0,2,3,0,1,3,0,1,2};
__constant__ int d_EOFV[4][3] = {{3,6,9},{0,7,10},{1,4,11},{2,5,8}};

typedef float f32x4 __attribute__((ext_vector_type(4)));
typedef short s16x8 __attribute__((ext_vector_type(8)));

static __device__ __forceinline__ float b2f(unsigned short u) {
    union { unsigned int i; float f; } x; x.i = ((unsigned int)u) << 16; return x.f;
}
static __device__ __forceinline__ unsigned short f2b(float f) {
    union { float f; unsigned int i; } x; x.f = f;
    unsigned int r = (x.i + 0x7fffu + ((x.i >> 16) & 1u)) >> 16;
    return (unsigned short)r;
}
static __device__ __forceinline__ float act_f(float v, int act) {
    if (act == 1) return fmaxf(v, 0.f);
    if (act == 2) return (v > 0.f) ? v : (__expf(v) - 1.f);
    return v;
}

#define GL2LDS(g, l) __builtin_amdgcn_global_load_lds(                     \
    (__attribute__((address_space(1))) void*)(g),                          \
    (__attribute__((address_space(3))) void*)(l), 16, 0, 0)

#define CS_STRIDE 136   // shorts per epilogue LDS row (128 + 8 pad), 16B aligned

// ================= MFMA bf16 GEMM (unchanged from round 10) ================
__global__ __launch_bounds__(256) void gemm_bf16(
    const unsigned short* __restrict__ A0, int Ka0, int K0,
    const unsigned short* __restrict__ A1, int Ka1, int K1,
    const unsigned short* __restrict__ WT, int Kw, int wtoff,
    unsigned short* __restrict__ C, int M, int N,
    const float* __restrict__ bias, int act,
    float* __restrict__ pstats, int accum,
    float* __restrict__ Cpart, int Ksl)
{
    __shared__ __align__(16) unsigned short SMEM[24576];
    int tid = threadIdx.x;
    int lane = tid & 63, wave = tid >> 6;
    int wr = wave >> 1, wc = wave & 1;
    int g = lane >> 4, r16 = lane & 15;

    int nct = N >> 7, nrt = M >> 7;
    int id = blockIdx.x, bx, by;
    if ((nrt & 7) == 0) {
        int grp = id / (nct * 8);
        int rem = id - grp * nct * 8;
        by = grp * 8 + (rem & 7);
        bx = rem >> 3;
    } else { bx = id % nct; by = id / nct; }
    int rowBase = by * 128;
    int colBase = bx * 128;
    int koff = blockIdx.z * Ksl;

    int u2 = lane >> 3;
    int q  = (lane & 7) ^ u2;
    int srow = wave * 32 + u2 * 2 + (q >> 2);
    int scol = (q & 3) * 8;
    const unsigned short* wrow  = WT + (size_t)(colBase + srow) * Kw + wtoff + scol;
    const unsigned short* wrow2 = WT + (size_t)(colBase + srow + 16) * Kw + wtoff + scol;

    f32x4 acc[4][4];
#pragma unroll
    for (int i = 0; i < 4; ++i)
#pragma unroll
        for (int j = 0; j < 4; ++j) acc[i][j] = (f32x4){0.f, 0.f, 0.f, 0.f};

#define STAGE_(kg_, SL_) do {                                                   \
        int kg = (kg_);                                                         \
        const unsigned short* Ap; int lda; int kc;                              \
        if (kg < K0) { Ap = A0; lda = Ka0; kc = kg; }                           \
        else         { Ap = A1; lda = Ka1; kc = kg - K0; }                      \
        const unsigned short* ga = Ap + (size_t)(rowBase + srow) * lda + kc + scol; \
        GL2LDS(ga, (SL_) + wave * 1024);                                        \
        GL2LDS(ga + (size_t)16 * lda, (SL_) + wave * 1024 + 512);               \
        GL2LDS(wrow + kg, (SL_) + 4096 + wave * 1024);                          \
        GL2LDS(wrow2 + kg, (SL_) + 4096 + wave * 1024 + 512);                   \
    } while (0)

    int nt = Ksl >> 5;
    STAGE_(koff, SMEM);
    if (nt > 1) STAGE_(koff + 32, SMEM + 8192);
    int cur = 0;
    int rh  = r16 >> 1;
    int sw8 = (((((r16 & 1) << 2) | g) ^ rh)) << 3;
    for (int t = 0; t < nt; ++t) {
        if (t + 1 < nt) asm volatile("s_waitcnt vmcnt(4)" ::: "memory");
        else            asm volatile("s_waitcnt vmcnt(0)" ::: "memory");
        __builtin_amdgcn_s_barrier();
        __builtin_amdgcn_sched_barrier(0);
        if (t + 2 < nt) {
            int nx = cur + 2; if (nx >= 3) nx -= 3;
            STAGE_(koff + (t + 2) * 32, SMEM + nx * 8192);
        }
        unsigned short* SA = SMEM + cur * 8192;
        unsigned short* SB = SA + 4096;
        s16x8 xf[4], wf[4];
#pragma unroll
        for (int j = 0; j < 4; ++j)
            xf[j] = *(const s16x8*)(SA + (wr * 32 + j * 8 + rh) * 64 + sw8);
#pragma unroll
        for (int i = 0; i < 4; ++i)
            wf[i] = *(const s16x8*)(SB + (wc * 32 + i * 8 + rh) * 64 + sw8);
#pragma unroll
        for (int i = 0; i < 4; ++i)
#pragma unroll
            for (int j = 0; j < 4; ++j)
                acc[i][j] = __builtin_amdgcn_mfma_f32_16x16x32_bf16(
                    wf[i], xf[j], acc[i][j], 0, 0, 0);
        cur = (cur == 2) ? 0 : cur + 1;
    }
#undef STAGE_
    __syncthreads();

    if (Cpart) {
#pragma unroll
        for (int j = 0; j < 4; ++j) {
            int row = rowBase + wr * 64 + j * 16 + r16;
#pragma unroll
            for (int i = 0; i < 4; ++i) {
                int col0 = colBase + wc * 64 + i * 16 + g * 4;
                float4 v = make_float4(acc[i][j][0], acc[i][j][1],
                                       acc[i][j][2], acc[i][j][3]);
                *(float4*)&Cpart[((size_t)blockIdx.z * M + row) * N + col0] = v;
            }
        }
        return;
    }

#pragma unroll
    for (int i = 0; i < 4; ++i) {
        int lc0 = wc * 64 + i * 16 + g * 4;
        float4 b4 = bias ? *(const float4*)(bias + colBase + lc0)
                         : make_float4(0.f, 0.f, 0.f, 0.f);
        float s[4] = {0.f, 0.f, 0.f, 0.f}, q2[4] = {0.f, 0.f, 0.f, 0.f};
#pragma unroll
        for (int j = 0; j < 4; ++j) {
            int lr = wr * 64 + j * 16 + r16;
            float v0 = act_f(acc[i][j][0] + b4.x, act);
            float v1 = act_f(acc[i][j][1] + b4.y, act);
            float v2 = act_f(acc[i][j][2] + b4.z, act);
            float v3 = act_f(acc[i][j][3] + b4.w, act);
            *(ushort4*)&SMEM[lr * CS_STRIDE + lc0] =
                make_ushort4(f2b(v0), f2b(v1), f2b(v2), f2b(v3));
            s[0] += v0; s[1] += v1; s[2] += v2; s[3] += v3;
            q2[0] += v0 * v0; q2[1] += v1 * v1; q2[2] += v2 * v2; q2[3] += v3 * v3;
        }
        if (pstats) {
#pragma unroll
            for (int p = 0; p < 4; ++p) {
#pragma unroll
                for (int d = 1; d < 16; d <<= 1) {
                    s[p] += __shfl_xor(s[p], d);
                    q2[p] += __shfl_xor(q2[p], d);
                }
            }
            if (r16 == 0) {
                float* pr = pstats + ((size_t)(by * 2 + wr)) * 1024 + colBase + lc0;
                float4 s4 = make_float4(s[0], s[1], s[2], s[3]);
                float4 q4 = make_float4(q2[0], q2[1], q2[2], q2[3]);
                if (accum) {
                    float4 o = *(float4*)pr;
                    s4.x += o.x; s4.y += o.y; s4.z += o.z; s4.w += o.w;
                    float4 o2 = *(float4*)(pr + 512);
                    q4.x += o2.x; q4.y += o2.y; q4.z += o2.z; q4.w += o2.w;
                }
                *(float4*)pr = s4;
                *(float4*)(pr + 512) = q4;
            }
        }
    }
    __syncthreads();
    {
        int qd = tid & 3;
        int rr = tid >> 2;
#pragma unroll
        for (int pass = 0; pass < 2; ++pass) {
            int lr = pass * 64 + rr;
            size_t grow = (size_t)(rowBase + lr) * N + colBase;
#pragma unroll
            for (int u = 0; u < 4; ++u) {
                int cofs = u * 32 + qd * 8;
                uint4 v = *(const uint4*)(SMEM + lr * CS_STRIDE + cofs);
                *(uint4*)&C[grow + cofs] = v;
            }
        }
    }
}

// ---- stats partial reduction: slot[t] = sum_r P[r][t], t in [0,1024) -------
__global__ __launch_bounds__(256) void finalize_stats_k(
    const float* __restrict__ P, int nrows, float* __restrict__ slot)
{
    __shared__ float red[256];
    int lane = threadIdx.x & 63;
    int seg  = threadIdx.x >> 6;          // 0..3
    int col  = blockIdx.x * 64 + lane;
    float s = 0.f;
    for (int r = seg; r < nrows; r += 4)
        s += P[(size_t)r * 1024 + col];
    red[threadIdx.x] = s;
    __syncthreads();
    if (seg == 0)
        slot[col] = red[lane] + red[64 + lane] + red[128 + lane] + red[192 + lane];
}

// ---- in-place BN finalize+apply (grid-stride, fully coalesced) -------------
__global__ __launch_bounds__(256) void bn_apply_k(
    unsigned short* __restrict__ X, long n4, int cmask4, int C,
    const float* __restrict__ slot, const float* __restrict__ gm,
    const float* __restrict__ bt, float inv_cnt, float premul, int act)
{
    __shared__ float sc_s[512], sh_s[512];
    for (int c = threadIdx.x; c < C; c += 256) {
        float mean = slot[c] * inv_cnt;
        float var = fmaxf(slot[512 + c] * inv_cnt - mean * mean, 0.f);
        float sc = gm[c] * rsqrtf(var + EPS_);
        sc_s[c] = sc * premul;
        sh_s[c] = bt[c] - mean * sc;
    }
    __syncthreads();
    long stride = (long)gridDim.x * 256;
    for (long i = (long)blockIdx.x * 256 + threadIdx.x; i < n4; i += stride) {
        ushort4 x = ((ushort4*)X)[i];
        int c = ((int)(i & cmask4)) * 4;
        unsigned short o[4] = {x.x, x.y, x.z, x.w};
#pragma unroll
        for (int e = 0; e < 4; ++e) {
            float v = b2f(o[e]) * sc_s[c + e] + sh_s[c + e];
            o[e] = f2b(act_f(v, act));
        }
        ((ushort4*)X)[i] = make_ushort4(o[0], o[1], o[2], o[3]);
    }
}

// ---- BN fold into consuming gemm (reads finalized slot) --------------------
// blocks 0..1023: WT[n][kof+k] *= sc[k]*premul (coalesced RMW)
// blocks 1024..1031: bias_out[n] = bias_in[n] + sum_k sh[k]*Wsrc[k*512+n]
__global__ __launch_bounds__(256) void fold_bn_k(
    const float* __restrict__ slot, const float* __restrict__ gm,
    const float* __restrict__ bt, float inv_cnt, float premul,
    unsigned short* __restrict__ WT, int Kw, int kof,
    const float* __restrict__ Wsrc, const float* __restrict__ bias_in,
    float* __restrict__ bias_out)
{
    int blk = blockIdx.x;
    if (blk < 1024) {
        int i = blk * 256 + threadIdx.x;
        int n = i >> 9, k = i & 511;
        float mean = slot[k] * inv_cnt;
        float var = fmaxf(slot[512 + k] * inv_cnt - mean * mean, 0.f);
        float sc = gm[k] * rsqrtf(var + EPS_) * premul;
        unsigned short* p = &WT[(size_t)n * Kw + kof + k];
        *p = f2b(b2f(*p) * sc);
    } else {
        __shared__ float red[256];
        int blk2 = blk - 1024;            // 0..7
        int lane = threadIdx.x & 63;
        int seg  = threadIdx.x >> 6;      // 0..3
        int n = blk2 * 64 + lane;
        float acc = 0.f;
        int k0 = seg * 128;
#pragma unroll 4
        for (int k = k0; k < k0 + 128; ++k) {
            float mean = slot[k] * inv_cnt;
            float var = fmaxf(slot[512 + k] * inv_cnt - mean * mean, 0.f);
            float sc = gm[k] * rsqrtf(var + EPS_);
            float sh = bt[k] - mean * sc;
            acc += sh * Wsrc[(size_t)k * 512 + n];
        }
        red[threadIdx.x] = acc;
        __syncthreads();
        if (seg == 0)
            bias_out[n] = (bias_in ? bias_in[n] : 0.f)
                        + red[lane] + red[64 + lane]
                        + red[128 + lane] + red[192 + lane];
    }
}

// ---- split-K combine, parallel + vectorized; stats -> partials -------------
__global__ __launch_bounds__(256) void combine_k(
    const float4* __restrict__ P, int S, int M,
    unsigned short* __restrict__ C, float* __restrict__ pstats, int act)
{
    int col4 = threadIdx.x & 127;
    int rh = threadIdx.x >> 7;
    int rb = blockIdx.y * 8;
    float4 s4 = make_float4(0.f, 0.f, 0.f, 0.f);
    float4 q4 = make_float4(0.f, 0.f, 0.f, 0.f);
#pragma unroll
    for (int i = 0; i < 4; ++i) {
        int row = rb + rh + 2 * i;
        float4 v = make_float4(0.f, 0.f, 0.f, 0.f);
#pragma unroll
        for (int z = 0; z < 8; ++z) {
            float4 p = P[((size_t)z * M + row) * 128 + col4];
            v.x += p.x; v.y += p.y; v.z += p.z; v.w += p.w;
        }
        v.x = act_f(v.x, act); v.y = act_f(v.y, act);
        v.z = act_f(v.z, act); v.w = act_f(v.w, act);
        ((ushort4*)C)[(size_t)row * 128 + col4] =
            make_ushort4(f2b(v.x), f2b(v.y), f2b(v.z), f2b(v.w));
        s4.x += v.x; s4.y += v.y; s4.z += v.z; s4.w += v.w;
        q4.x += v.x * v.x; q4.y += v.y * v.y; q4.z += v.z * v.z; q4.w += v.w * v.w;
    }
    __shared__ float4 sb[256], qb[256];
    sb[threadIdx.x] = s4; qb[threadIdx.x] = q4;
    __syncthreads();
    if (threadIdx.x < 128) {
        float4 a = sb[threadIdx.x], b = sb[threadIdx.x + 128];
        float4 c = qb[threadIdx.x], d = qb[threadIdx.x + 128];
        int col = threadIdx.x * 4;
        float* pr = pstats + (size_t)blockIdx.y * 1024 + col;
        *(float4*)pr = make_float4(a.x + b.x, a.y + b.y, a.z + b.z, a.w + b.w);
        *(float4*)(pr + 512) = make_float4(c.x + d.x, c.y + d.y, c.z + d.z, c.w + d.w);
    }
}

// ---- batched weight convert+transpose, LDS-tiled ---------------------------
#define NTD 13
struct TBatch {
    const float* src[NTD];
    unsigned short* dst[NTD];
    int K[NTD];
    int tbase[NTD + 1];
};
__global__ __launch_bounds__(256) void transpose_batch_k(TBatch tb)
{
    int id = blockIdx.x;
    int d = 0;
#pragma unroll
    for (int j = 0; j < NTD; ++j) if (id >= tb.tbase[j + 1]) d = j + 1;
    int rel = id - tb.tbase[d];
    int kt = rel >> 3, ntl = rel & 7;
    int k0 = kt * 64, n0 = ntl * 64;
    const float* S = tb.src[d];
    unsigned short* D = tb.dst[d];
    int K = tb.K[d];
    __shared__ unsigned short L[64][68];
    int c = threadIdx.x & 63;
    int r = threadIdx.x >> 6;
#pragma unroll
    for (int p = 0; p < 16; ++p) {
        int kk = r + p * 4;
        L[kk][c] = f2b(S[(size_t)(k0 + kk) * 512 + n0 + c]);
    }
    __syncthreads();
#pragma unroll
    for (int p = 0; p < 16; ++p) {
        int nn = r + p * 4;
        D[(size_t)(n0 + nn) * K + k0 + c] = L[c][nn];
    }
}

// fused P/Q transpose for m1_w1 [1024,512], LDS-tiled (two 512x512 halves)
__global__ __launch_bounds__(256) void transpose_pq_k(
    const float* __restrict__ W, unsigned short* __restrict__ WT)
{
    int id = blockIdx.x;
    int kt = id >> 4, ntl = id & 15;
    int k0 = kt * 64, n0 = ntl * 64;
    __shared__ unsigned short L[64][68];
    int c = threadIdx.x & 63;
    int r = threadIdx.x >> 6;
    int nb = n0 + c;
    const float* S = (n0 < 512) ? (W + nb) : (W + (size_t)512 * 512 + (nb - 512));
#pragma unroll
    for (int p = 0; p < 16; ++p) {
        int kk = r + p * 4;
        L[kk][c] = f2b(S[(size_t)(k0 + kk) * 512]);
    }
    __syncthreads();
#pragma unroll
    for (int p = 0; p < 16; ++p) {
        int nn = r + p * 4;
        WT[(size_t)(n0 + nn) * 512 + k0 + c] = L[c][nn];
    }
}

// ---- column stats over Y1 [NROW, 256] bf16 -> PSTATS rows 0..255 -----------
__global__ __launch_bounds__(256) void colstats_k(
    const unsigned short* __restrict__ X, float* __restrict__ P)
{
    __shared__ float sb[256][4], qb[256][4];
    int c4 = threadIdx.x & 63;
    int seg = threadIdx.x >> 6;
    int r0 = blockIdx.x * 128;
    float s[4] = {0.f, 0.f, 0.f, 0.f}, q[4] = {0.f, 0.f, 0.f, 0.f};
    for (int r = r0 + seg; r < r0 + 128; r += 4) {
        ushort4 x = ((const ushort4*)X)[(size_t)r * 64 + c4];
        float v0 = b2f(x.x), v1 = b2f(x.y), v2 = b2f(x.z), v3 = b2f(x.w);
        s[0] += v0; s[1] += v1; s[2] += v2; s[3] += v3;
        q[0] += v0 * v0; q[1] += v1 * v1; q[2] += v2 * v2; q[3] += v3 * v3;
    }
#pragma unroll
    for (int e = 0; e < 4; ++e) { sb[threadIdx.x][e] = s[e]; qb[threadIdx.x][e] = q[e]; }
    __syncthreads();
    if (threadIdx.x < 64) {
        int c = threadIdx.x;
        float4 S, Q;
        S.x = sb[c][0] + sb[c + 64][0] + sb[c + 128][0] + sb[c + 192][0];
        S.y = sb[c][1] + sb[c + 64][1] + sb[c + 128][1] + sb[c + 192][1];
        S.z = sb[c][2] + sb[c + 64][2] + sb[c + 128][2] + sb[c + 192][2];
        S.w = sb[c][3] + sb[c + 64][3] + sb[c + 128][3] + sb[c + 192][3];
        Q.x = qb[c][0] + qb[c + 64][0] + qb[c + 128][0] + qb[c + 192][0];
        Q.y = qb[c][1] + qb[c + 64][1] + qb[c + 128][1] + qb[c + 192][1];
        Q.z = qb[c][2] + qb[c + 64][2] + qb[c + 128][2] + qb[c + 192][2];
        Q.w = qb[c][3] + qb[c + 64][3] + qb[c + 128][3] + qb[c + 192][3];
        *(float4*)&P[(size_t)blockIdx.x * 1024 + c * 4] = S;
        *(float4*)&P[(size_t)blockIdx.x * 1024 + 512 + c * 4] = Q;
    }
}

// ---------------- misc ------------------------------------------------------
// merged input builders: blocks [0,512) build X0, [512,8704) build CE
__global__ __launch_bounds__(256) void build_inputs_k(
    const float* __restrict__ box, float* __restrict__ X0,
    const int* __restrict__ cats, const float* __restrict__ emb,
    unsigned short* __restrict__ CE)
{
    if (blockIdx.x < 512) {
        int i = blockIdx.x * 256 + threadIdx.x;      // NROW*4 = 131072
        int c = i & 3; int r = i >> 2;
        int t = r & 15; int bv = r >> 4; int v = bv & 3; int b = bv >> 2;
        X0[i] = box[(((size_t)b * Tt + t) * Vv + v) * 4 + c];
    } else {
        int i = (blockIdx.x - 512) * 256 + threadIdx.x;   // NROW*64
        int c4 = i & 63; int r = i >> 6;
        int t = r & 15; int bv = r >> 4; int v = bv & 3; int b = bv >> 2;
        int cat = cats[((size_t)b * Tt + t) * Vv + v];
        unsigned short o[4];
#pragma unroll
        for (int e = 0; e < 4; ++e)
            o[e] = (cat == 0) ? 0 : f2b(emb[cat * 256 + c4 * 4 + e]);
        ((ushort4*)CE)[(size_t)r * 64 + c4] = make_ushort4(o[0], o[1], o[2], o[3]);
    }
}

__global__ __launch_bounds__(256) void smallk_gemm_k(
    const float* __restrict__ X0, const float* __restrict__ W4,
    unsigned short* __restrict__ Y1)
{
    int i = blockIdx.x * 256 + threadIdx.x;
    if (i >= NROW * 64) return;
    int n4 = i & 63; int m = i >> 6;
    float4 x = *(const float4*)(X0 + m * 4);
    unsigned short o[4];
#pragma unroll
    for (int e = 0; e < 4; ++e) {
        int n = n4 * 4 + e;
        float v = x.x * W4[n] + x.y * W4[256 + n] + x.z * W4[512 + n] + x.w * W4[768 + n];
        o[e] = f2b(v);
    }
    ((ushort4*)Y1)[(size_t)m * 64 + n4] = make_ushort4(o[0], o[1], o[2], o[3]);
}

__global__ __launch_bounds__(256) void edge_gather_k(
    const unsigned short* __restrict__ PQ,
    const float* __restrict__ b1, unsigned short* __restrict__ E)
{
    int i = blockIdx.x * 256 + threadIdx.x;
    if (i >= CROWS_E * 128) return;
    int c4 = i & 127; int m = i >> 7;
    int t = m & 15; int be = m >> 4; int e = be % 12; int brel = be / 12;
    int s = d_SEND[e], r = d_RECV[e];
    ushort4 p = ((const ushort4*)PQ)[(((size_t)brel * 4 + s) * 16 + t) * 256 + c4];
    ushort4 q = ((const ushort4*)PQ)[(((size_t)brel * 4 + r) * 16 + t) * 256 + 128 + c4];
    unsigned short pa[4] = {p.x, p.y, p.z, p.w}, qa[4] = {q.x, q.y, q.z, q.w}, o[4];
#pragma unroll
    for (int e2 = 0; e2 < 4; ++e2) {
        float v = b2f(pa[e2]) + b2f(qa[e2]) + b1[c4 * 4 + e2];
        o[e2] = f2b(act_f(v, 2));
    }
    ((ushort4*)E)[i] = make_ushort4(o[0], o[1], o[2], o[3]);
}

__global__ __launch_bounds__(256) void edge_agg_k(
    const unsigned short* __restrict__ E2c, unsigned short* __restrict__ nraw, int b0)
{
    int i = blockIdx.x * 256 + threadIdx.x;
    if (i >= CB * Vv * Tt * 128) return;
    int c4 = i & 127; int r = i >> 7;
    int t = r & 15; int r2 = r >> 4; int v = r2 & 3; int brel = r2 >> 2;
    float s[4] = {0.f, 0.f, 0.f, 0.f};
#pragma unroll
    for (int j = 0; j < 3; ++j) {
        int e = d_EOFV[v][j];
        ushort4 x = ((const ushort4*)E2c)[(((size_t)brel * 12 + e) * 16 + t) * 128 + c4];
        s[0] += b2f(x.x); s[1] += b2f(x.y); s[2] += b2f(x.z); s[3] += b2f(x.w);
    }
    ((ushort4*)nraw)[((((size_t)(b0 + brel)) * 4 + v) * 16 + t) * 128 + c4] =
        make_ushort4(f2b(s[0]), f2b(s[1]), f2b(s[2]), f2b(s[3]));
}

__global__ __launch_bounds__(256) void feat_mean_k(
    const unsigned short* __restrict__ q, unsigned short* __restrict__ feat)
{
    int i = blockIdx.x * 256 + threadIdx.x;
    if (i >= Bb * 128) return;
    int c4 = i & 127; int b = i >> 7;
    float s[4] = {0.f, 0.f, 0.f, 0.f};
#pragma unroll
    for (int v = 0; v < 4; ++v) {
        ushort4 x = ((const ushort4*)q)[(((size_t)b * 4 + v)) * 128 + c4];
        s[0] += b2f(x.x); s[1] += b2f(x.y); s[2] += b2f(x.z); s[3] += b2f(x.w);
    }
    ((ushort4*)feat)[(size_t)b * 128 + c4] = make_ushort4(
        f2b(0.25f * s[0]), f2b(0.25f * s[1]), f2b(0.25f * s[2]), f2b(0.25f * s[3]));
}

__global__ __launch_bounds__(256) void final_gemm_k(
    const unsigned short* __restrict__ H2, const float* __restrict__ W,
    const float* __restrict__ b, float* __restrict__ out)
{
    __shared__ float Ls[4 * 512];
    int m0 = blockIdx.x * 4;
    for (int i = threadIdx.x; i < 512; i += 256) {
        ushort4 x = ((const ushort4*)H2)[(size_t)m0 * 128 + i];
        *(float4*)&Ls[i * 4] = make_float4(b2f(x.x), b2f(x.y), b2f(x.z), b2f(x.w));
    }
    __syncthreads();
    int n = threadIdx.x;
    if (n >= NCc) return;
    float a0 = b[n], a1 = a0, a2 = a0, a3 = a0;
#pragma unroll 8
    for (int k = 0; k < 512; ++k) {
        float w = W[(size_t)k * NCc + n];
        a0 += Ls[k] * w;
        a1 += Ls[512 + k] * w;
        a2 += Ls[1024 + k] * w;
        a3 += Ls[1536 + k] * w;
    }
    out[(size_t)m0 * NCc + n] = a0;
    out[(size_t)(m0 + 1) * NCc + n] = a1;
    out[(size_t)(m0 + 2) * NCc + n] = a2;
    out[(size_t)(m0 + 3) * NCc + n] = a3;
}

__global__ __launch_bounds__(256) void copy_labels_k(
    const int* __restrict__ lab, float* __restrict__ out)
{
    int i = blockIdx.x * 256 + threadIdx.x;
    if (i < Bb) out[i] = (float)lab[i];
}

// ---------------- host-side helpers -----------------------------------------
static inline void gemm(hipStream_t s,
                        const unsigned short* A0, int Ka0, int K0,
                        const unsigned short* A1, int Ka1, int K1,
                        const unsigned short* WT, int Kw, int wtoff,
                        unsigned short* C, int M, int N,
                        const float* bias, int act, float* pstats, int accum)
{
    dim3 g((N / 128) * (M / 128), 1, 1);
    hipLaunchKernelGGL(gemm_bf16, g, dim3(256), 0, s,
                       A0, Ka0, K0, A1, Ka1, K1, WT, Kw, wtoff, C, M, N,
                       bias, act, pstats, accum, (float*)nullptr, K0 + K1);
}

static inline void bn_apply(hipStream_t s, unsigned short* X, long n, int C,
                            const float* P, int nrows, float* slot,
                            const float* gm, const float* bt,
                            float cnt, float premul, int act)
{
    hipLaunchKernelGGL(finalize_stats_k, dim3(16), dim3(256), 0, s, P, nrows, slot);
    long n4 = n / 4;
    long nb = (n4 + 255) / 256;
    if (nb > 1024) nb = 1024;
    hipLaunchKernelGGL(bn_apply_k, dim3((unsigned)nb), dim3(256), 0, s,
                       X, n4, C / 4 - 1, C, slot, gm, bt, 1.f / cnt, premul, act);
}

static inline void fold_bn(hipStream_t s, const float* P, int nrows, float* slot,
                           const float* gm, const float* bt, float cnt,
                           float premul, unsigned short* WT, int Kw, int kof,
                           const float* Wsrc, const float* bias_in, float* bias_out)
{
    hipLaunchKernelGGL(finalize_stats_k, dim3(16), dim3(256), 0, s, P, nrows, slot);
    hipLaunchKernelGGL(fold_bn_k, dim3(1032), dim3(256), 0, s,
                       slot, gm, bt, 1.f / cnt, premul, WT, Kw, kof,
                       Wsrc, bias_in, bias_out);
}

extern "C" void kernel_launch(void* const* d_in, const int* in_sizes, int n_in,
                              void* d_out, int out_size, void* d_ws, size_t ws_size,
                              hipStream_t stream)
{
    const int*   box_cat = (const int*)  d_in[1];
    const float* box_in  = (const float*)d_in[2];
    const int*   vlabel  = (const int*)  d_in[4];
    const float* emb     = (const float*)d_in[5];
    const float* c2f_w1  = (const float*)d_in[6];
    const float* c2f_g1  = (const float*)d_in[7];
    const float* c2f_b1  = (const float*)d_in[8];
    const float* c2f_w2  = (const float*)d_in[9];
    const float* c2f_g2  = (const float*)d_in[10];
    const float* c2f_b2  = (const float*)d_in[11];
    const float* fus_w   = (const float*)d_in[12];
    const float* fus_g   = (const float*)d_in[13];
    const float* fus_b   = (const float*)d_in[14];
    const float* m1_w1   = (const float*)d_in[15];
    const float* m1_b1   = (const float*)d_in[16];
    const float* m1_w2   = (const float*)d_in[17];
    const float* m1_b2   = (const float*)d_in[18];
    const float* m1_g    = (const float*)d_in[19];
    const float* m1_bb   = (const float*)d_in[20];
    const float* m2_w1   = (const float*)d_in[21];
    const float* m2_b1   = (const float*)d_in[22];
    const float* m2_w2   = (const float*)d_in[23];
    const float* m2_b2   = (const float*)d_in[24];
    const float* m2_g    = (const float*)d_in[25];
    const float* m2_bb   = (const float*)d_in[26];
    const float* t1_w1   = (const float*)d_in[27];
    const float* t1_b1   = (const float*)d_in[28];
    const float* t1_w2   = (const float*)d_in[29];
    const float* t1_b2   = (const float*)d_in[30];
    const float* t1_g    = (const float*)d_in[31];
    const float* t1_bb   = (const float*)d_in[32];
    const float* ps_w1   = (const float*)d_in[33];
    const float* ps_g1   = (const float*)d_in[34];
    const float* ps_b1   = (const float*)d_in[35];
    const float* ps_w2   = (const float*)d_in[36];
    const float* ps_g2   = (const float*)d_in[37];
    const float* ps_b2   = (const float*)d_in[38];
    const float* tb_w1   = (const float*)d_in[39];
    const float* tb_g1   = (const float*)d_in[40];
    const float* tb_b1   = (const float*)d_in[41];
    const float* tb_w2   = (const float*)d_in[42];
    const float* tb_g2   = (const float*)d_in[43];
    const float* tb_b2   = (const float*)d_in[44];
    const float* cl_w1   = (const float*)d_in[45];
    const float* cl_b1   = (const float*)d_in[46];
    const float* cl_w2   = (const float*)d_in[47];
    const float* cl_b2   = (const float*)d_in[48];
    const float* cl_w3   = (const float*)d_in[49];
    const float* cl_b3   = (const float*)d_in[50];

    float* out = (float*)d_out;

    // ---------------- workspace layout (bytes) ------------------------------
    char* base = (char*)d_ws;
    const size_t SZ_ACT = (size_t)NROW * 512 * 2;       // 32 MB
    unsigned short* A0v = (unsigned short*)(base);
    unsigned short* A1v = (unsigned short*)(base + SZ_ACT);
    char* Sreg = base + 2 * SZ_ACT;                     // scratch region
    unsigned short* A2v = (unsigned short*)Sreg;
    unsigned short* CE  = (unsigned short*)Sreg;
    unsigned short* Y1  = (unsigned short*)(Sreg + (size_t)NROW * 256 * 2);
    unsigned short* PQc = (unsigned short*)Sreg;
    unsigned short* EC1 = (unsigned short*)(Sreg + (size_t)CROWS_N * 1024 * 2);
    unsigned short* EC2 = (unsigned short*)(Sreg + (size_t)CROWS_N * 1024 * 2
                                                 + (size_t)CROWS_E * 512 * 2);
    float* Ppart = (float*)Sreg;
    char* wtb = Sreg + (size_t)CROWS_N * 1024 * 2 + 2 * (size_t)CROWS_E * 512 * 2;
    unsigned short* wtp = (unsigned short*)wtb;
    size_t wo = 0;
    auto alloc_wt = [&](int K) { unsigned short* p = wtp + wo; wo += (size_t)K * 512; return p; };
    unsigned short* WTc2f2 = alloc_wt(256);
    unsigned short* WTfus  = alloc_wt(768);
    unsigned short* WTpq   = alloc_wt(1024);
    unsigned short* WTm1b  = alloc_wt(512);
    unsigned short* WTm2a  = alloc_wt(512);
    unsigned short* WTm2b  = alloc_wt(512);
    unsigned short* WTt1a  = alloc_wt(1024);
    unsigned short* WTt1b  = alloc_wt(512);
    unsigned short* WTps1  = alloc_wt(512);
    unsigned short* WTps2  = alloc_wt(512);
    unsigned short* WTtb1  = alloc_wt(8192);
    unsigned short* WTtb2  = alloc_wt(512);
    unsigned short* WTcl1  = alloc_wt(512);
    unsigned short* WTcl2  = alloc_wt(512);
    float* X0f    = (float*)(wtp + wo);
    float* STATS  = X0f + (size_t)NROW * 4;   // slot scratch
    float* PSTATS = STATS + 10 * 1024;        // 512 rows x 1024 f32 = 2 MB
    float* BIASF  = PSTATS + 512 * 1024;      // 3 x 512 f32 folded biases

    auto slot = [&](int i) { return STATS + (size_t)i * 1024; };

    // 0. weight prep (no zeroing: PSTATS rows initialized by '=' writes;
    //    m1b chunk 0 uses accum=0 -- stats-pollution fix)
    {
        TBatch tb;
        const float* srcs[NTD] = {c2f_w2, fus_w, m1_w2, m2_w1, m2_w2, t1_w1, t1_w2,
                                  ps_w1, ps_w2, tb_w1, tb_w2, cl_w1, cl_w2};
        unsigned short* dsts[NTD] = {WTc2f2, WTfus, WTm1b, WTm2a, WTm2b, WTt1a, WTt1b,
                                     WTps1, WTps2, WTtb1, WTtb2, WTcl1, WTcl2};
        int Ks[NTD] = {256, 768, 512, 512, 512, 1024, 512, 512, 512, 8192, 512, 512, 512};
        int acc = 0;
        for (int i = 0; i < NTD; ++i) {
            tb.src[i] = srcs[i]; tb.dst[i] = dsts[i]; tb.K[i] = Ks[i];
            tb.tbase[i] = acc; acc += (Ks[i] / 64) * 8;
        }
        tb.tbase[NTD] = acc;
        hipLaunchKernelGGL(transpose_batch_k, dim3((unsigned)acc), dim3(256), 0,
                           stream, tb);
    }
    hipLaunchKernelGGL(transpose_pq_k, dim3(128), dim3(256), 0, stream, m1_w1, WTpq);

    // 1. inputs (merged builder)
    hipLaunchKernelGGL(build_inputs_k, dim3(512 + NROW * 64 / 256), dim3(256), 0,
                       stream, box_in, X0f, box_cat, emb, CE);

    // 2. c2f layer 1 (K=4 fp32) -> Y1 [NROW,256]; stats; finalize+BN+ReLU
    hipLaunchKernelGGL(smallk_gemm_k, dim3((NROW * 64 + 255) / 256), dim3(256), 0,
                       stream, X0f, c2f_w1, Y1);
    hipLaunchKernelGGL(colstats_k, dim3(NROW / 128), dim3(256), 0, stream, Y1, PSTATS);
    bn_apply(stream, Y1, (long)NROW * 256, 256, PSTATS, NROW / 128, slot(0),
             c2f_g1, c2f_b1, (float)NROW, 1.f, 1);

    // 3. c2f layer 2 -> A1 (stats fused); finalize+BN+ReLU
    gemm(stream, Y1, 256, 256, nullptr, 0, 0, WTc2f2, 256, 0, A1v, NROW, 512,
         nullptr, 0, PSTATS, 0);
    bn_apply(stream, A1v, (long)NROW * 512, 512, PSTATS, 512, slot(1),
             c2f_g2, c2f_b2, (float)NROW, 1.f, 1);

    // 4. fusion dual-K -> A0 (BF); finalize+BN+ReLU
    gemm(stream, A1v, 512, 512, CE, 256, 256, WTfus, 768, 0, A0v, NROW, 512,
         nullptr, 0, PSTATS, 0);
    bn_apply(stream, A0v, (long)NROW * 512, 512, PSTATS, 512, slot(2),
             fus_g, fus_b, (float)NROW, 1.f, 1);                      // BF in A0

    // 5-7. edge pipeline chunked; node sums -> A1; chunk 0 initializes PSTATS
    for (int c = 0; c < NCHUNK; ++c) {
        const unsigned short* BFc = A0v + (size_t)c * CROWS_N * 512;
        gemm(stream, BFc, 512, 512, nullptr, 0, 0, WTpq, 512, 0, PQc, CROWS_N, 1024,
             nullptr, 0, nullptr, 0);
        hipLaunchKernelGGL(edge_gather_k, dim3((CROWS_E * 128 + 255) / 256), dim3(256),
                           0, stream, PQc, m1_b1, EC1);
        gemm(stream, EC1, 512, 512, nullptr, 0, 0, WTm1b, 512, 0, EC2, CROWS_E, 512,
             m1_b2, 2, PSTATS, (c > 0) ? 1 : 0);
        hipLaunchKernelGGL(edge_agg_k, dim3((CB * Vv * Tt * 128 + 255) / 256), dim3(256),
                           0, stream, EC2, A1v, c * CB);
    }
    // FOLD m1 BN (act=0, premul=1/3) into m2a weights
    fold_bn(stream, PSTATS, 384, slot(3), m1_g, m1_bb, (float)EROW, 1.f / 3.f,
            WTm2a, 512, 0, m2_w1, m2_b1, BIASF);

    // 8. m2 MLP (m2a consumes folded BN)
    gemm(stream, A1v, 512, 512, nullptr, 0, 0, WTm2a, 512, 0, A2v, NROW, 512,
         BIASF, 2, nullptr, 0);
    gemm(stream, A2v, 512, 512, nullptr, 0, 0, WTm2b, 512, 0, A1v, NROW, 512,
         m2_b2, 2, PSTATS, 0);
    fold_bn(stream, PSTATS, 512, slot(4), m2_g, m2_bb, (float)NROW, 1.f,
            WTt1a, 1024, 0, t1_w1, t1_b1, BIASF + 512);

    // 9. t1 MLP on cat(n2_raw, BF)
    gemm(stream, A1v, 512, 512, A0v, 512, 512, WTt1a, 1024, 0, A2v, NROW, 512,
         BIASF + 512, 2, nullptr, 0);
    gemm(stream, A2v, 512, 512, nullptr, 0, 0, WTt1b, 512, 0, A1v, NROW, 512,
         t1_b2, 2, PSTATS, 0);
    fold_bn(stream, PSTATS, 512, slot(5), t1_g, t1_bb, (float)NROW, 1.f,
            WTps1, 512, 0, ps_w1, nullptr, BIASF + 1024);

    // 10. ps (ps1 consumes folded BN); finalize+BN+ReLU each layer
    gemm(stream, A1v, 512, 512, nullptr, 0, 0, WTps1, 512, 0, A2v, NROW, 512,
         BIASF + 1024, 0, PSTATS, 0);
    bn_apply(stream, A2v, (long)NROW * 512, 512, PSTATS, 512, slot(6),
             ps_g1, ps_b1, (float)NROW, 1.f, 1);

    gemm(stream, A2v, 512, 512, nullptr, 0, 0, WTps2, 512, 0, A0v, NROW, 512,
         nullptr, 0, PSTATS, 0);
    bn_apply(stream, A0v, (long)NROW * 512, 512, PSTATS, 512, slot(7),
             ps_g2, ps_b2, (float)NROW, 1.f, 1);                      // p_final in A0

    // 11. tb1 split-K=8 (A0 viewed [2048 x 8192]); partials; combine -> A1
    {
        dim3 g((512 / 128) * (2048 / 128), 1, 8);
        hipLaunchKernelGGL(gemm_bf16, g, dim3(256), 0, stream,
                           A0v, 8192, 8192, (const unsigned short*)nullptr, 0, 0,
                           WTtb1, 8192, 0, A1v, 2048, 512,
                           (const float*)nullptr, 0, (float*)nullptr, 0, Ppart, 1024);
        hipLaunchKernelGGL(combine_k, dim3(1, 2048 / 8), dim3(256), 0, stream,
                           (const float4*)Ppart, 8, 2048, A1v, PSTATS, 0);
    }
    bn_apply(stream, A1v, (long)Bb * Vv * 512, 512, PSTATS, 2048 / 8, slot(8),
             tb_g1, tb_b1, (float)(Bb * Vv), 1.f, 1);

    gemm(stream, A1v, 512, 512, nullptr, 0, 0, WTtb2, 512, 0, A2v, Bb * Vv, 512,
         nullptr, 0, PSTATS, 0);
    bn_apply(stream, A2v, (long)Bb * Vv * 512, 512, PSTATS, (Bb * Vv / 128) * 2,
             slot(9), tb_g2, tb_b2, (float)(Bb * Vv), 1.f, 1);        // q2 in A2

    // 12. feat mean -> A0 (512x512)
    hipLaunchKernelGGL(feat_mean_k, dim3((Bb * 128 + 255) / 256), dim3(256), 0, stream,
                       A2v, A0v);

    // 13. classifier (no BN)
    gemm(stream, A0v, 512, 512, nullptr, 0, 0, WTcl1, 512, 0, A1v, Bb, 512,
         cl_b1, 1, nullptr, 0);
    gemm(stream, A1v, 512, 512, nullptr, 0, 0, WTcl2, 512, 0, A2v, Bb, 512,
         cl_b2, 1, nullptr, 0);
    hipLaunchKernelGGL(final_gemm_k, dim3(Bb / 4), dim3(256), 0, stream,
                       A2v, cl_w3, cl_b3, out);

    // 14. labels
    hipLaunchKernelGGL(copy_labels_k, dim3((Bb + 255) / 256), dim3(256), 0, stream,
                       vlabel, out + (size_t)Bb * NCc);
}